// Round 3
// baseline (2012.238 us; speedup 1.0000x reference)
//
#include <hip/hip_runtime.h>
#include <math.h>

#define B_LEN 1024
#define T_LEN 256
#define HST 36   // hid_sh leading stride keeps float4 access conflict-light
#define TS 20    // dxT/ypT row stride (17 used + 3 pad): banks 20*r%32 distinct

__device__ __forceinline__ float fast_rcp(float x) { return __builtin_amdgcn_rcpf(x); }
__device__ __forceinline__ float fast_rsq(float x) { return __builtin_amdgcn_rsqf(x); }
__device__ __forceinline__ float lane_bcast(float v, int l) {
    return __int_as_float(__builtin_amdgcn_readlane(__float_as_int(v), l));
}
__device__ __forceinline__ float fast_tanh(float x) {
    float e = __expf(2.0f * x);
    return 1.0f - 2.0f * fast_rcp(e + 1.0f);
}
__device__ __forceinline__ float softplus_f(float x) {
    return (x > 20.0f) ? x : log1pf(expf(x));
}
// weighted 17-dot: 0.0625*sum(all 17) + (2-0.0625)*center  (Wc0=2, rest 1/16)
__device__ __forceinline__ float wdot17(const float* __restrict__ a,
                                        const float* __restrict__ b) {
    float full = 0.0f;
    #pragma unroll
    for (int c = 0; c < 4; ++c) {
        const float4 av = *(const float4*)&a[c * 4];
        const float4 bv = *(const float4*)&b[c * 4];
        full += av.x * bv.x + av.y * bv.y + av.z * bv.z + av.w * bv.w;
    }
    full += a[16] * b[16];
    return 0.0625f * full + 1.9375f * a[0] * b[0];
}

// TWO BATCHES PER WAVE (64-thread blocks, grid=512). ILP latency hiding:
// the R2 single-wave kernel was 80% stall at 1 wave/SIMD (9200 cyc/step,
// ~1900 issue-cyc). Full A/B register-level duplication gives each wave two
// independent dependence chains that fill each other's stalls: LDS
// round-trips, readlane chains, transcendentals. Same lane layouts per
// batch (readlane stays wave-uniform), zero barriers, weights shared.
// LDS arrays doubled (~22 KB/block, 2 blocks/CU).
__global__ __launch_bounds__(64, 1)
void ukf_kernel(const float* __restrict__ X0, const float* __restrict__ U,
                const float* __restrict__ Y,  const float* __restrict__ W1,
                const float* __restrict__ B1, const float* __restrict__ W2,
                const float* __restrict__ B2, const float* __restrict__ HM,
                const float* __restrict__ LQ, const float* __restrict__ LR,
                const float* __restrict__ LP0, float* __restrict__ out)
{
    const int lane = threadIdx.x;     // 0..63, one wave
    const int blk  = blockIdx.x;      // 0..511, batches 2*blk, 2*blk+1
    const int k8   = lane & 7;        // column / j8
    const int g8   = lane >> 3;       // row group / i8
    const int i8   = g8;
    const int j8   = k8;
    const int h32  = lane & 31;
    const int p2   = lane >> 5;       // half-wave (L1 row parity)
    const int m4   = lane & 3;
    const int sy   = lane >> 2;       // 0..15

    __shared__ __align__(16) float u_sh[2][T_LEN * 2];
    __shared__ __align__(16) float y_sh[2][T_LEN * 4];
    __shared__ __align__(16) float pts_sh[2][17 * 8];
    __shared__ __align__(16) float hid_sh[2][17 * HST];
    __shared__ __align__(16) float pf_sh[2][17 * 8];
    __shared__ __align__(16) float dxT_sh[2][8 * TS];   // dxT[d][s]
    __shared__ __align__(16) float ypT_sh[2][4 * TS];   // ypT[m][s]
    __shared__ __align__(16) float xp_sh[2][8];
    __shared__ __align__(16) float ypred_sh[2][4];
    __shared__ __align__(16) float Sy_sh[2][16];
    __shared__ __align__(16) float Pxy_sh[2][32];
    __shared__ __align__(16) float K_sh[2][32];
    __shared__ __align__(16) float Pp_sh[2][64];

    // ---- one-time staging (vectorized), both batches ----
    #pragma unroll
    for (int q = 0; q < 2; ++q) {
        const int b = (blk << 1) + q;
        const float4* Uv = (const float4*)(U + (size_t)b * (T_LEN * 2));
        float4* us = (float4*)u_sh[q];
        #pragma unroll
        for (int k = 0; k < 2; ++k) us[k * 64 + lane] = Uv[k * 64 + lane];
        const float4* Yv = (const float4*)(Y + (size_t)b * (T_LEN * 4));
        float4* ys = (float4*)y_sh[q];
        #pragma unroll
        for (int k = 0; k < 4; ++k) ys[k * 64 + lane] = Yv[k * 64 + lane];
    }

    // shared (batch-independent) weights
    float w1r[10];
    #pragma unroll
    for (int d = 0; d < 10; ++d) w1r[d] = W1[d * 32 + h32];
    const float b1r = B1[h32];
    float w2r[32];
    #pragma unroll
    for (int h = 0; h < 32; ++h) w2r[h] = W2[h * 8 + k8];
    const float b2r = B2[k8];
    float hmr[8];
    #pragma unroll
    for (int d = 0; d < 8; ++d) hmr[d] = HM[m4 * 8 + d];

    const float qdiag = softplus_f(LQ[g8]);
    const float rdiag = softplus_f(LR[m4]);
    const float p0k   = softplus_f(LP0[k8]);

    size_t Xbase[2], Pbase[2], qbase[2], rbase[2];
    #pragma unroll
    for (int q = 0; q < 2; ++q) {
        const int b = (blk << 1) + q;
        Xbase[q] = (size_t)b * T_LEN * 8;
        Pbase[q] = (size_t)B_LEN * T_LEN * 8  + (size_t)b * T_LEN * 64;
        qbase[q] = (size_t)B_LEN * T_LEN * 72 + (size_t)b * T_LEN;
        rbase[q] = (size_t)B_LEN * T_LEN * 73 + (size_t)b * T_LEN;
    }

    // ---- persistent register state per batch: x replicated, P col k8 ----
    float xn[2][8], Pc[2][8], Ppc[2][8];
    #pragma unroll
    for (int q = 0; q < 2; ++q) {
        const int b = (blk << 1) + q;
        const float4 xa = *(const float4*)&X0[b * 8];
        const float4 xb = *(const float4*)&X0[b * 8 + 4];
        xn[q][0] = xa.x; xn[q][1] = xa.y; xn[q][2] = xa.z; xn[q][3] = xa.w;
        xn[q][4] = xb.x; xn[q][5] = xb.y; xn[q][6] = xb.z; xn[q][7] = xb.w;
        #pragma unroll
        for (int i = 0; i < 8; ++i) {
            Pc[q][i]  = (i == k8) ? p0k : 0.0f;
            Ppc[q][i] = (i == k8) ? 1.0f : 0.0f;   // identity -> deferred qe(0)=0
        }
        out[Pbase[q] + lane] = Pc[q][g8];          // coalesced 64-lane P store
        if (lane == 0) {
            *(float4*)&out[Xbase[q]]     = make_float4(xn[q][0], xn[q][1], xn[q][2], xn[q][3]);
            *(float4*)&out[Xbase[q] + 4] = make_float4(xn[q][4], xn[q][5], xn[q][6], xn[q][7]);
            out[rbase[q]] = 0.0f;
        }
    }

    for (int t = 1; t < T_LEN; ++t) {
        // ===== S1: fused branchless column-chol8(8P+jit) + prev-step qe-LDL ==
        #pragma unroll
        for (int q = 0; q < 2; ++q) {
            float a[8];
            #pragma unroll
            for (int i = 0; i < 8; ++i) a[i] = 8.0f * Pc[q][i] + ((i == k8) ? 1e-4f : 0.0f);
            float qe = 0.0f;
            #pragma unroll
            for (int j = 0; j < 8; ++j) {
                const float dj = lane_bcast(a[j], j);
                const float dq = lane_bcast(Ppc[q][j], j);
                const float rv = fast_rsq(dj);
                const float rq = fast_rcp(dq);
                qe += __logf(dq);
                const float sc = (k8 == j) ? rv : 1.0f;
                const float tc = (k8 > j) ? a[j] * (rv * rv) : 0.0f;
                const float tq = (k8 > j) ? Ppc[q][j] * rq : 0.0f;
                float uc[8], uq[8];
                #pragma unroll
                for (int i = j + 1; i < 8; ++i) {
                    uc[i] = lane_bcast(a[i], j);
                    uq[i] = lane_bcast(Ppc[q][i], j);
                }
                #pragma unroll
                for (int i = j + 1; i < 8; ++i) {
                    a[i]      = sc * a[i] - tc * uc[i];       // k8==j: *rv; k8>j: rank-1
                    Ppc[q][i] = fmaf(-tq, uq[i], Ppc[q][i]);  // LDL diag elim
                }
                a[j] = (k8 == j) ? dj * rv : a[j];
            }
            if (lane == 0) out[qbase[q] + (t - 1)] = 0.5f * qe;

            // sigma points -> LDS (rows: 0 center, 1..8 +L, 9..16 -L)
            float Lc[8];
            #pragma unroll
            for (int i = 0; i < 8; ++i) Lc[i] = (i >= k8) ? a[i] : 0.0f;
            if (g8 == 0) {
                *(float4*)&pts_sh[q][(1 + k8) * 8] =
                    make_float4(xn[q][0] + Lc[0], xn[q][1] + Lc[1], xn[q][2] + Lc[2], xn[q][3] + Lc[3]);
                *(float4*)&pts_sh[q][(1 + k8) * 8 + 4] =
                    make_float4(xn[q][4] + Lc[4], xn[q][5] + Lc[5], xn[q][6] + Lc[6], xn[q][7] + Lc[7]);
            } else if (g8 == 1) {
                *(float4*)&pts_sh[q][(9 + k8) * 8] =
                    make_float4(xn[q][0] - Lc[0], xn[q][1] - Lc[1], xn[q][2] - Lc[2], xn[q][3] - Lc[3]);
                *(float4*)&pts_sh[q][(9 + k8) * 8 + 4] =
                    make_float4(xn[q][4] - Lc[4], xn[q][5] - Lc[5], xn[q][6] - Lc[6], xn[q][7] - Lc[7]);
            } else if (g8 == 2 && k8 == 0) {
                *(float4*)&pts_sh[q][0] = make_float4(xn[q][0], xn[q][1], xn[q][2], xn[q][3]);
                *(float4*)&pts_sh[q][4] = make_float4(xn[q][4], xn[q][5], xn[q][6], xn[q][7]);
            }
        }

        // ===== S2: NN layer 1 + layer 2, both batches ========================
        #pragma unroll
        for (int q = 0; q < 2; ++q) {
            const float u0 = u_sh[q][(t - 1) * 2 + 0];
            const float u1 = u_sh[q][(t - 1) * 2 + 1];
            const float ub = b1r + u0 * w1r[8] + u1 * w1r[9];
            #pragma unroll
            for (int p = 0; p < 8; ++p) {
                const int s = 2 * p + p2;                 // rows 0..15
                const float4 pa = *(const float4*)&pts_sh[q][s * 8];
                const float4 pb = *(const float4*)&pts_sh[q][s * 8 + 4];
                float acc = ub
                    + pa.x * w1r[0] + pa.y * w1r[1] + pa.z * w1r[2] + pa.w * w1r[3]
                    + pb.x * w1r[4] + pb.y * w1r[5] + pb.z * w1r[6] + pb.w * w1r[7];
                hid_sh[q][s * HST + h32] = fast_tanh(acc);
            }
            if (p2 == 0) {                                // row 16
                const float4 pa = *(const float4*)&pts_sh[q][16 * 8];
                const float4 pb = *(const float4*)&pts_sh[q][16 * 8 + 4];
                float acc = ub
                    + pa.x * w1r[0] + pa.y * w1r[1] + pa.z * w1r[2] + pa.w * w1r[3]
                    + pb.x * w1r[4] + pb.y * w1r[5] + pb.z * w1r[6] + pb.w * w1r[7];
                hid_sh[q][16 * HST + h32] = fast_tanh(acc);
            }
            // layer 2: rows 0-7, 8-15 (64 lanes = 8 rows x 8 outs), then row 16
            #pragma unroll
            for (int rr = 0; rr < 2; ++rr) {
                const int srow = rr * 8 + g8;
                float acc = b2r;
                #pragma unroll
                for (int h = 0; h < 32; h += 4) {
                    const float4 hv = *(const float4*)&hid_sh[q][srow * HST + h];
                    acc += hv.x * w2r[h] + hv.y * w2r[h + 1] + hv.z * w2r[h + 2] + hv.w * w2r[h + 3];
                }
                pf_sh[q][srow * 8 + k8] = pts_sh[q][srow * 8 + k8] + acc;
            }
            if (lane < 8) {
                float a16 = b2r;
                #pragma unroll
                for (int h = 0; h < 32; h += 4) {
                    const float4 hv = *(const float4*)&hid_sh[q][16 * HST + h];
                    a16 += hv.x * w2r[h] + hv.y * w2r[h + 1] + hv.z * w2r[h + 2] + hv.w * w2r[h + 3];
                }
                pf_sh[q][16 * 8 + lane] = pts_sh[q][16 * 8 + lane] + a16;
            }
        }

        // ===== S3: x_pred + dxT, then y_pts + ypred + ypT ====================
        #pragma unroll
        for (int q = 0; q < 2; ++q) {
            {
                const float v0   = pf_sh[q][i8 * 8 + j8];
                const float v1   = pf_sh[q][(8 + i8) * 8 + j8];
                const float pf16 = (i8 == 0) ? pf_sh[q][16 * 8 + j8] : 0.0f;
                float part = ((i8 == 0) ? pf16 : v0) + v1;    // s=16 replaces s=0
                part += __shfl_xor(part, 8);
                part += __shfl_xor(part, 16);
                part += __shfl_xor(part, 32);
                const float xp = part * 0.0625f;
                if (i8 == 0) xp_sh[q][j8] = xp;
                dxT_sh[q][j8 * TS + i8]     = v0 - xp;        // dxT[d][s]
                dxT_sh[q][j8 * TS + 8 + i8] = v1 - xp;
                if (i8 == 0) dxT_sh[q][j8 * TS + 16] = pf16 - xp;
            }
            {
                float yv0, yv16 = 0.0f;
                {
                    const float4 pa = *(const float4*)&pf_sh[q][sy * 8];
                    const float4 pb = *(const float4*)&pf_sh[q][sy * 8 + 4];
                    yv0 = pa.x * hmr[0] + pa.y * hmr[1] + pa.z * hmr[2] + pa.w * hmr[3]
                        + pb.x * hmr[4] + pb.y * hmr[5] + pb.z * hmr[6] + pb.w * hmr[7];
                }
                if (sy == 0) {
                    const float4 pa = *(const float4*)&pf_sh[q][16 * 8];
                    const float4 pb = *(const float4*)&pf_sh[q][16 * 8 + 4];
                    yv16 = pa.x * hmr[0] + pa.y * hmr[1] + pa.z * hmr[2] + pa.w * hmr[3]
                         + pb.x * hmr[4] + pb.y * hmr[5] + pb.z * hmr[6] + pb.w * hmr[7];
                }
                float py = (sy == 0) ? yv16 : yv0;
                py += __shfl_xor(py, 4);
                py += __shfl_xor(py, 8);
                py += __shfl_xor(py, 16);
                py += __shfl_xor(py, 32);
                const float ypred = py * 0.0625f;
                if (lane < 4) ypred_sh[q][lane] = ypred;
                ypT_sh[q][m4 * TS + sy] = yv0 - ypred;        // ypT[m][s]
                if (sy == 0) ypT_sh[q][m4 * TS + 16] = yv16 - ypred;
            }
        }

        // ===== S4: covariances (Ppred; merged Pxy+Sy round; Ppc readback) ====
        #pragma unroll
        for (int q = 0; q < 2; ++q) {
            const float pv = wdot17(&dxT_sh[q][i8 * TS], &dxT_sh[q][j8 * TS])
                           + ((i8 == j8) ? (qdiag + 1e-4f) : 0.0f);
            Pp_sh[q][lane] = pv;

            const int r2 = (lane < 32) ? sy : (sy & 3);
            const float* pa2 = (lane < 32) ? &dxT_sh[q][r2 * TS] : &ypT_sh[q][r2 * TS];
            float v2 = wdot17(pa2, &ypT_sh[q][m4 * TS]);
            v2 += ((lane >= 32) && (r2 == m4)) ? rdiag : 0.0f;
            if (lane < 32)      Pxy_sh[q][lane] = v2;
            else if (lane < 48) Sy_sh[q][r2 * 4 + m4] = v2;

            #pragma unroll
            for (int i = 0; i < 8; ++i) Ppc[q][i] = Pp_sh[q][i * 8 + k8];  // in-order
        }

        // ===== S5+S6 per batch: chol4(Sy)->Si, r_e, K, P_new, x_new, stores ==
        #pragma unroll
        for (int q = 0; q < 2; ++q) {
            float Si[16];
            {
                const float4 r0v = *(const float4*)&Sy_sh[q][0];
                const float4 r1v = *(const float4*)&Sy_sh[q][4];
                const float4 r2v = *(const float4*)&Sy_sh[q][8];
                const float4 r3v = *(const float4*)&Sy_sh[q][12];
                const float d0 = r0v.x;
                const float r0 = fast_rsq(d0);
                const float L10 = r1v.x * r0, L20 = r2v.x * r0, L30 = r3v.x * r0;
                const float d1 = r1v.y - L10 * L10;
                const float r1 = fast_rsq(d1);
                const float L21 = (r2v.y - L20 * L10) * r1;
                const float L31 = (r3v.y - L30 * L10) * r1;
                const float d2_ = r2v.z - L20 * L20 - L21 * L21;
                const float rr2 = fast_rsq(d2_);
                const float L32 = (r3v.z - L30 * L20 - L31 * L21) * rr2;
                const float d3 = r3v.w - L30 * L30 - L31 * L31 - L32 * L32;
                const float r3 = fast_rsq(d3);
                if (lane == 0)
                    out[rbase[q] + t] = 0.5f * (__logf(d0) + __logf(d1) + __logf(d2_) + __logf(d3));
                float z1 = -L10 * r0 * r1;
                float z2 = -(L20 * r0 + L21 * z1) * rr2;
                float z3 = -(L30 * r0 + L31 * z1 + L32 * z2) * r3;
                float c03 = z3 * r3;
                float c02 = (z2 - L32 * c03) * rr2;
                float c01 = (z1 - L21 * c02 - L31 * c03) * r1;
                float c00 = (r0 - L10 * c01 - L20 * c02 - L30 * c03) * r0;
                float z2b = -L21 * r1 * rr2;
                float z3b = -(L31 * r1 + L32 * z2b) * r3;
                float c13 = z3b * r3;
                float c12 = (z2b - L32 * c13) * rr2;
                float c11 = (r1 - L21 * c12 - L31 * c13) * r1;
                float c10 = (-L10 * c11 - L20 * c12 - L30 * c13) * r0;
                float z3c = -L32 * rr2 * r3;
                float c23 = z3c * r3;
                float c22 = (rr2 - L32 * c23) * rr2;
                float c21 = (-L21 * c22 - L31 * c23) * r1;
                float c20 = (-L10 * c21 - L20 * c22 - L30 * c23) * r0;
                float c33 = r3 * r3;
                float c32 = (-L32 * c33) * rr2;
                float c31 = (-L21 * c32 - L31 * c33) * r1;
                float c30 = (-L10 * c31 - L20 * c32 - L30 * c33) * r0;
                const float s01 = 0.5f * (c01 + c10), s02 = 0.5f * (c02 + c20);
                const float s03 = 0.5f * (c03 + c30), s12 = 0.5f * (c12 + c21);
                const float s13 = 0.5f * (c13 + c31), s23 = 0.5f * (c23 + c32);
                Si[0]  = c00; Si[1]  = s01; Si[2]  = s02; Si[3]  = s03;
                Si[4]  = s01; Si[5]  = c11; Si[6]  = s12; Si[7]  = s13;
                Si[8]  = s02; Si[9]  = s12; Si[10] = c22; Si[11] = s23;
                Si[12] = s03; Si[13] = s13; Si[14] = s23; Si[15] = c33;
            }

            const float4 pr = *(const float4*)&Pxy_sh[q][k8 * 4];     // Pxy row k8
            float kk[4];
            #pragma unroll
            for (int aa = 0; aa < 4; ++aa)
                kk[aa] = pr.x * Si[0 * 4 + aa] + pr.y * Si[1 * 4 + aa]
                       + pr.z * Si[2 * 4 + aa] + pr.w * Si[3 * 4 + aa];
            if (g8 == 0) *(float4*)&K_sh[q][k8 * 4] = make_float4(kk[0], kk[1], kk[2], kk[3]);
            float K_[32];
            #pragma unroll
            for (int r = 0; r < 8; ++r) {
                const float4 kr = *(const float4*)&K_sh[q][r * 4];    // in-order
                K_[r * 4 + 0] = kr.x; K_[r * 4 + 1] = kr.y;
                K_[r * 4 + 2] = kr.z; K_[r * 4 + 3] = kr.w;
            }
            // P_new column k8 = Ppc - K * Pxy[k8,:]^T  (+ jitter). Ppc regs
            // survive into next iteration's deferred qe-LDL.
            #pragma unroll
            for (int i = 0; i < 8; ++i) {
                const float m = K_[i * 4 + 0] * pr.x + K_[i * 4 + 1] * pr.y
                              + K_[i * 4 + 2] * pr.z + K_[i * 4 + 3] * pr.w;
                Pc[q][i] = Ppc[q][i] - m + ((i == k8) ? 1e-4f : 0.0f);
            }
            const float4 yt = *(const float4*)&y_sh[q][t * 4];
            const float4 yp = *(const float4*)&ypred_sh[q][0];
            const float in0 = yt.x - yp.x, in1 = yt.y - yp.y;
            const float in2 = yt.z - yp.z, in3 = yt.w - yp.w;
            const float4 xpa = *(const float4*)&xp_sh[q][0];
            const float4 xpb = *(const float4*)&xp_sh[q][4];
            const float xpv[8] = {xpa.x, xpa.y, xpa.z, xpa.w, xpb.x, xpb.y, xpb.z, xpb.w};
            #pragma unroll
            for (int i = 0; i < 8; ++i)
                xn[q][i] = xpv[i] + K_[i * 4 + 0] * in0 + K_[i * 4 + 1] * in1
                                  + K_[i * 4 + 2] * in2 + K_[i * 4 + 3] * in3;
            out[Pbase[q] + (size_t)t * 64 + lane] = Pc[q][g8];
            if (lane == 0) {
                *(float4*)&out[Xbase[q] + (size_t)t * 8]     = make_float4(xn[q][0], xn[q][1], xn[q][2], xn[q][3]);
                *(float4*)&out[Xbase[q] + (size_t)t * 8 + 4] = make_float4(xn[q][4], xn[q][5], xn[q][6], xn[q][7]);
            }
        }
    }

    // final deferred qe for t = T_LEN-1, both batches
    #pragma unroll
    for (int q = 0; q < 2; ++q) {
        float qe = 0.0f;
        #pragma unroll
        for (int j = 0; j < 8; ++j) {
            const float dq = lane_bcast(Ppc[q][j], j);
            const float rq = fast_rcp(dq);
            qe += __logf(dq);
            const float tq = (k8 > j) ? Ppc[q][j] * rq : 0.0f;
            float uq[8];
            #pragma unroll
            for (int i = j + 1; i < 8; ++i) uq[i] = lane_bcast(Ppc[q][i], j);
            #pragma unroll
            for (int i = j + 1; i < 8; ++i) Ppc[q][i] = fmaf(-tq, uq[i], Ppc[q][i]);
        }
        if (lane == 0) out[qbase[q] + (T_LEN - 1)] = 0.5f * qe;
    }
}

extern "C" void kernel_launch(void* const* d_in, const int* in_sizes, int n_in,
                              void* d_out, int out_size, void* d_ws, size_t ws_size,
                              hipStream_t stream) {
    (void)in_sizes; (void)n_in; (void)out_size; (void)d_ws; (void)ws_size;
    const float* X0 = (const float*)d_in[0];
    const float* U  = (const float*)d_in[1];
    const float* Y  = (const float*)d_in[2];
    const float* W1 = (const float*)d_in[3];
    const float* B1 = (const float*)d_in[4];
    const float* W2 = (const float*)d_in[5];
    const float* B2 = (const float*)d_in[6];
    const float* HM = (const float*)d_in[7];
    const float* LQ = (const float*)d_in[8];
    const float* LR = (const float*)d_in[9];
    const float* LP0 = (const float*)d_in[10];
    float* out = (float*)d_out;
    ukf_kernel<<<dim3(B_LEN / 2), dim3(64), 0, stream>>>(X0, U, Y, W1, B1, W2, B2,
                                                         HM, LQ, LR, LP0, out);
}

// Round 4
// 1257.332 us; speedup vs baseline: 1.6004x; 1.6004x over previous
//
#include <hip/hip_runtime.h>
#include <math.h>

#define B_LEN 1024
#define T_LEN 256
#define HST 36   // hid_sh leading stride keeps float4 access conflict-light
#define TS 20    // dxT/ypT row stride (17 used + 3 pad): banks 20*r%32 distinct

__device__ __forceinline__ float fast_rcp(float x) { return __builtin_amdgcn_rcpf(x); }
__device__ __forceinline__ float fast_rsq(float x) { return __builtin_amdgcn_rsqf(x); }
__device__ __forceinline__ float lane_bcast(float v, int l) {
    return __int_as_float(__builtin_amdgcn_readlane(__float_as_int(v), l));
}
__device__ __forceinline__ float fast_tanh(float x) {
    float e = __expf(2.0f * x);
    return 1.0f - 2.0f * fast_rcp(e + 1.0f);
}
__device__ __forceinline__ float softplus_f(float x) {
    return (x > 20.0f) ? x : log1pf(expf(x));
}
// weighted 17-dot: 0.0625*sum(all 17) + (2-0.0625)*center  (Wc0=2, rest 1/16)
__device__ __forceinline__ float wdot17(const float* __restrict__ a,
                                        const float* __restrict__ b) {
    float full = 0.0f;
    #pragma unroll
    for (int c = 0; c < 4; ++c) {
        const float4 av = *(const float4*)&a[c * 4];
        const float4 bv = *(const float4*)&b[c * 4];
        full += av.x * bv.x + av.y * bv.y + av.z * bv.z + av.w * bv.w;
    }
    full += a[16] * b[16];
    return 0.0625f * full + 1.9375f * a[0] * b[0];
}

// 8 INDEPENDENT SINGLE-WAVE BATCH MACHINES PER BLOCK (512 threads, grid=128).
// R2's verified barrier-free 1-wave/batch kernel, re-geometried: a block's 8
// waves land round-robin on the CU's 4 SIMDs -> 2 co-resident waves/SIMD.
// The HARDWARE interleaves them (R3 proved the compiler won't interleave two
// batch chains in one wave: exactly 2x, zero overlap). Each wave's ~50% stall
// time is filled by its SIMD sibling. No barriers anywhere; waves never
// communicate. u/y staging dropped (LDS 40KB for 8 wave contexts < 64KB);
// u_t / y_t read direct from global at step top, ~600cyc before first use.
__global__ __launch_bounds__(512, 2)
void ukf_kernel(const float* __restrict__ X0, const float* __restrict__ U,
                const float* __restrict__ Y,  const float* __restrict__ W1,
                const float* __restrict__ B1, const float* __restrict__ W2,
                const float* __restrict__ B2, const float* __restrict__ HM,
                const float* __restrict__ LQ, const float* __restrict__ LR,
                const float* __restrict__ LP0, float* __restrict__ out)
{
    const int tid  = threadIdx.x;
    const int wid  = tid >> 6;        // 0..7: which batch machine
    const int lane = tid & 63;
    const int b    = (blockIdx.x << 3) + wid;
    const int k8   = lane & 7;        // column / j8
    const int g8   = lane >> 3;       // row group / i8
    const int i8   = g8;
    const int j8   = k8;
    const int h32  = lane & 31;
    const int p2   = lane >> 5;       // half-wave (L1 row parity)
    const int m4   = lane & 3;
    const int sy   = lane >> 2;       // 0..15

    // per-wave LDS contexts (8 waves/block): 8*1280 floats = 40 KB
    __shared__ __align__(16) float pts_sh[8][17 * 8];
    __shared__ __align__(16) float hid_sh[8][17 * HST];
    __shared__ __align__(16) float pf_sh[8][17 * 8];
    __shared__ __align__(16) float dxT_sh[8][8 * TS];   // dxT[d][s]
    __shared__ __align__(16) float ypT_sh[8][4 * TS];   // ypT[m][s]
    __shared__ __align__(16) float xp_sh[8][8];
    __shared__ __align__(16) float ypred_sh[8][4];
    __shared__ __align__(16) float Sy_sh[8][16];
    __shared__ __align__(16) float Pxy_sh[8][32];
    __shared__ __align__(16) float K_sh[8][32];
    __shared__ __align__(16) float Pp_sh[8][64];

    float* const pts  = pts_sh[wid];
    float* const hid  = hid_sh[wid];
    float* const pf   = pf_sh[wid];
    float* const dxT  = dxT_sh[wid];
    float* const ypT  = ypT_sh[wid];
    float* const xp_  = xp_sh[wid];
    float* const ypr  = ypred_sh[wid];
    float* const Sy_  = Sy_sh[wid];
    float* const Pxy  = Pxy_sh[wid];
    float* const K_s  = K_sh[wid];
    float* const Pp_  = Pp_sh[wid];

    float w1r[10];
    #pragma unroll
    for (int d = 0; d < 10; ++d) w1r[d] = W1[d * 32 + h32];
    const float b1r = B1[h32];
    float w2r[32];
    #pragma unroll
    for (int h = 0; h < 32; ++h) w2r[h] = W2[h * 8 + k8];
    const float b2r = B2[k8];
    float hmr[8];
    #pragma unroll
    for (int d = 0; d < 8; ++d) hmr[d] = HM[m4 * 8 + d];

    const float qdiag = softplus_f(LQ[g8]);
    const float rdiag = softplus_f(LR[m4]);

    const size_t ub_ofs = (size_t)b * (T_LEN * 2);
    const size_t yb_ofs = (size_t)b * (T_LEN * 4);
    const size_t Xbase = (size_t)b * T_LEN * 8;
    const size_t Pbase = (size_t)B_LEN * T_LEN * 8  + (size_t)b * T_LEN * 64;
    const size_t qbase = (size_t)B_LEN * T_LEN * 72 + (size_t)b * T_LEN;
    const size_t rbase = (size_t)B_LEN * T_LEN * 73 + (size_t)b * T_LEN;

    // ---- persistent register state: x replicated, P column k8, Ppred col k8 ----
    float xn[8], Pc[8], Ppc[8];
    {
        const float4 xa = *(const float4*)&X0[b * 8];
        const float4 xb = *(const float4*)&X0[b * 8 + 4];
        xn[0] = xa.x; xn[1] = xa.y; xn[2] = xa.z; xn[3] = xa.w;
        xn[4] = xb.x; xn[5] = xb.y; xn[6] = xb.z; xn[7] = xb.w;
        const float p0k = softplus_f(LP0[k8]);
        #pragma unroll
        for (int i = 0; i < 8; ++i) {
            Pc[i]  = (i == k8) ? p0k : 0.0f;
            Ppc[i] = (i == k8) ? 1.0f : 0.0f;   // identity -> deferred qe(0)=0
        }
    }
    out[Pbase + lane] = Pc[g8];                  // coalesced 64-lane P store
    if (lane == 0) {
        *(float4*)&out[Xbase]     = make_float4(xn[0], xn[1], xn[2], xn[3]);
        *(float4*)&out[Xbase + 4] = make_float4(xn[4], xn[5], xn[6], xn[7]);
        out[rbase] = 0.0f;
    }

    for (int t = 1; t < T_LEN; ++t) {
        // per-step inputs, issued early (consumed in S2 / S6, ~600+ cyc away)
        const float u0 = U[ub_ofs + (t - 1) * 2 + 0];
        const float u1 = U[ub_ofs + (t - 1) * 2 + 1];
        const float4 ytv = *(const float4*)&Y[yb_ofs + (size_t)t * 4];

        // ===== S1: fused branchless column-chol8(8P+jit) + prev-step qe-LDL ==
        float a[8];
        #pragma unroll
        for (int i = 0; i < 8; ++i) a[i] = 8.0f * Pc[i] + ((i == k8) ? 1e-4f : 0.0f);
        float qe = 0.0f;
        #pragma unroll
        for (int j = 0; j < 8; ++j) {
            const float dj = lane_bcast(a[j], j);
            const float dq = lane_bcast(Ppc[j], j);
            const float rv = fast_rsq(dj);
            const float rq = fast_rcp(dq);
            qe += __logf(dq);
            const float sc = (k8 == j) ? rv : 1.0f;
            const float tc = (k8 > j) ? a[j] * (rv * rv) : 0.0f;
            const float tq = (k8 > j) ? Ppc[j] * rq : 0.0f;
            float uc[8], uq[8];
            #pragma unroll
            for (int i = j + 1; i < 8; ++i) {
                uc[i] = lane_bcast(a[i], j);
                uq[i] = lane_bcast(Ppc[i], j);
            }
            #pragma unroll
            for (int i = j + 1; i < 8; ++i) {
                a[i]   = sc * a[i] - tc * uc[i];       // k8==j: *rv; k8>j: rank-1
                Ppc[i] = fmaf(-tq, uq[i], Ppc[i]);     // Gaussian elim (LDL diag)
            }
            a[j] = (k8 == j) ? dj * rv : a[j];
        }
        if (lane == 0) out[qbase + (t - 1)] = 0.5f * qe;

        // sigma points -> LDS (rows: 0 center, 1..8 +L, 9..16 -L)
        {
            float Lc[8];
            #pragma unroll
            for (int i = 0; i < 8; ++i) Lc[i] = (i >= k8) ? a[i] : 0.0f;
            if (g8 == 0) {
                *(float4*)&pts[(1 + k8) * 8] =
                    make_float4(xn[0] + Lc[0], xn[1] + Lc[1], xn[2] + Lc[2], xn[3] + Lc[3]);
                *(float4*)&pts[(1 + k8) * 8 + 4] =
                    make_float4(xn[4] + Lc[4], xn[5] + Lc[5], xn[6] + Lc[6], xn[7] + Lc[7]);
            } else if (g8 == 1) {
                *(float4*)&pts[(9 + k8) * 8] =
                    make_float4(xn[0] - Lc[0], xn[1] - Lc[1], xn[2] - Lc[2], xn[3] - Lc[3]);
                *(float4*)&pts[(9 + k8) * 8 + 4] =
                    make_float4(xn[4] - Lc[4], xn[5] - Lc[5], xn[6] - Lc[6], xn[7] - Lc[7]);
            } else if (g8 == 2 && k8 == 0) {
                *(float4*)&pts[0] = make_float4(xn[0], xn[1], xn[2], xn[3]);
                *(float4*)&pts[4] = make_float4(xn[4], xn[5], xn[6], xn[7]);
            }
        }

        // ===== S2: NN layer 1 (17 rows x 32 hidden; 2 rows/iter via p2) ======
        {
            const float ub = b1r + u0 * w1r[8] + u1 * w1r[9];
            #pragma unroll
            for (int p = 0; p < 8; ++p) {
                const int s = 2 * p + p2;                 // rows 0..15
                const float4 pa = *(const float4*)&pts[s * 8];
                const float4 pb = *(const float4*)&pts[s * 8 + 4];
                float acc = ub
                    + pa.x * w1r[0] + pa.y * w1r[1] + pa.z * w1r[2] + pa.w * w1r[3]
                    + pb.x * w1r[4] + pb.y * w1r[5] + pb.z * w1r[6] + pb.w * w1r[7];
                hid[s * HST + h32] = fast_tanh(acc);
            }
            if (p2 == 0) {                                // row 16
                const float4 pa = *(const float4*)&pts[16 * 8];
                const float4 pb = *(const float4*)&pts[16 * 8 + 4];
                float acc = ub
                    + pa.x * w1r[0] + pa.y * w1r[1] + pa.z * w1r[2] + pa.w * w1r[3]
                    + pb.x * w1r[4] + pb.y * w1r[5] + pb.z * w1r[6] + pb.w * w1r[7];
                hid[16 * HST + h32] = fast_tanh(acc);
            }
        }
        // layer 2: rows 0-7, 8-15 (64 lanes = 8 rows x 8 outs), then row 16
        #pragma unroll
        for (int rr = 0; rr < 2; ++rr) {
            const int srow = rr * 8 + g8;
            float acc = b2r;
            #pragma unroll
            for (int h = 0; h < 32; h += 4) {
                const float4 hv = *(const float4*)&hid[srow * HST + h];
                acc += hv.x * w2r[h] + hv.y * w2r[h + 1] + hv.z * w2r[h + 2] + hv.w * w2r[h + 3];
            }
            pf[srow * 8 + k8] = pts[srow * 8 + k8] + acc;
        }
        if (lane < 8) {
            float a16 = b2r;
            #pragma unroll
            for (int h = 0; h < 32; h += 4) {
                const float4 hv = *(const float4*)&hid[16 * HST + h];
                a16 += hv.x * w2r[h] + hv.y * w2r[h + 1] + hv.z * w2r[h + 2] + hv.w * w2r[h + 3];
            }
            pf[16 * 8 + lane] = pts[16 * 8 + lane] + a16;
        }

        // ===== S3: x_pred + dxT, then y_pts + ypred + ypT (same wave) ========
        {
            const float v0   = pf[i8 * 8 + j8];
            const float v1   = pf[(8 + i8) * 8 + j8];
            const float pf16 = (i8 == 0) ? pf[16 * 8 + j8] : 0.0f;
            float part = ((i8 == 0) ? pf16 : v0) + v1;    // s=16 replaces s=0
            part += __shfl_xor(part, 8);
            part += __shfl_xor(part, 16);
            part += __shfl_xor(part, 32);
            const float xp = part * 0.0625f;
            if (i8 == 0) xp_[j8] = xp;
            dxT[j8 * TS + i8]     = v0 - xp;              // dxT[d][s]
            dxT[j8 * TS + 8 + i8] = v1 - xp;
            if (i8 == 0) dxT[j8 * TS + 16] = pf16 - xp;
        }
        {
            float yv0, yv16 = 0.0f;
            {
                const float4 pa = *(const float4*)&pf[sy * 8];
                const float4 pb = *(const float4*)&pf[sy * 8 + 4];
                yv0 = pa.x * hmr[0] + pa.y * hmr[1] + pa.z * hmr[2] + pa.w * hmr[3]
                    + pb.x * hmr[4] + pb.y * hmr[5] + pb.z * hmr[6] + pb.w * hmr[7];
            }
            if (sy == 0) {
                const float4 pa = *(const float4*)&pf[16 * 8];
                const float4 pb = *(const float4*)&pf[16 * 8 + 4];
                yv16 = pa.x * hmr[0] + pa.y * hmr[1] + pa.z * hmr[2] + pa.w * hmr[3]
                     + pb.x * hmr[4] + pb.y * hmr[5] + pb.z * hmr[6] + pb.w * hmr[7];
            }
            float py = (sy == 0) ? yv16 : yv0;
            py += __shfl_xor(py, 4);
            py += __shfl_xor(py, 8);
            py += __shfl_xor(py, 16);
            py += __shfl_xor(py, 32);
            const float ypred = py * 0.0625f;
            if (lane < 4) ypr[lane] = ypred;
            ypT[m4 * TS + sy] = yv0 - ypred;              // ypT[m][s]
            if (sy == 0) ypT[m4 * TS + 16] = yv16 - ypred;
        }

        // ===== S4: covariances. Round1: Ppred (64 lanes). ====================
        // Round2 merged: lanes<32 -> Pxy(ii,mm); lanes 32..47 -> Sy(s2,m4).
        {
            const float pv = wdot17(&dxT[i8 * TS], &dxT[j8 * TS])
                           + ((i8 == j8) ? (qdiag + 1e-4f) : 0.0f);
            Pp_[lane] = pv;

            const int r2 = (lane < 32) ? sy : (sy & 3);
            const float* pa2 = (lane < 32) ? &dxT[r2 * TS] : &ypT[r2 * TS];
            float v2 = wdot17(pa2, &ypT[m4 * TS]);
            v2 += ((lane >= 32) && (r2 == m4)) ? rdiag : 0.0f;
            if (lane < 32)      Pxy[lane] = v2;
            else if (lane < 48) Sy_[r2 * 4 + m4] = v2;

            #pragma unroll
            for (int i = 0; i < 8; ++i) Ppc[i] = Pp_[i * 8 + k8];  // in-order
        }

        // ===== S5: replicated chol4(Sy) -> Sy^-1 in registers + r_e ==========
        float Si[16];
        {
            const float4 r0v = *(const float4*)&Sy_[0];
            const float4 r1v = *(const float4*)&Sy_[4];
            const float4 r2v = *(const float4*)&Sy_[8];
            const float4 r3v = *(const float4*)&Sy_[12];
            const float d0 = r0v.x;
            const float r0 = fast_rsq(d0);
            const float L10 = r1v.x * r0, L20 = r2v.x * r0, L30 = r3v.x * r0;
            const float d1 = r1v.y - L10 * L10;
            const float r1 = fast_rsq(d1);
            const float L21 = (r2v.y - L20 * L10) * r1;
            const float L31 = (r3v.y - L30 * L10) * r1;
            const float d2_ = r2v.z - L20 * L20 - L21 * L21;
            const float rr2 = fast_rsq(d2_);
            const float L32 = (r3v.z - L30 * L20 - L31 * L21) * rr2;
            const float d3 = r3v.w - L30 * L30 - L31 * L31 - L32 * L32;
            const float r3 = fast_rsq(d3);
            if (lane == 0)
                out[rbase + t] = 0.5f * (__logf(d0) + __logf(d1) + __logf(d2_) + __logf(d3));
            float z1 = -L10 * r0 * r1;
            float z2 = -(L20 * r0 + L21 * z1) * rr2;
            float z3 = -(L30 * r0 + L31 * z1 + L32 * z2) * r3;
            float c03 = z3 * r3;
            float c02 = (z2 - L32 * c03) * rr2;
            float c01 = (z1 - L21 * c02 - L31 * c03) * r1;
            float c00 = (r0 - L10 * c01 - L20 * c02 - L30 * c03) * r0;
            float z2b = -L21 * r1 * rr2;
            float z3b = -(L31 * r1 + L32 * z2b) * r3;
            float c13 = z3b * r3;
            float c12 = (z2b - L32 * c13) * rr2;
            float c11 = (r1 - L21 * c12 - L31 * c13) * r1;
            float c10 = (-L10 * c11 - L20 * c12 - L30 * c13) * r0;
            float z3c = -L32 * rr2 * r3;
            float c23 = z3c * r3;
            float c22 = (rr2 - L32 * c23) * rr2;
            float c21 = (-L21 * c22 - L31 * c23) * r1;
            float c20 = (-L10 * c21 - L20 * c22 - L30 * c23) * r0;
            float c33 = r3 * r3;
            float c32 = (-L32 * c33) * rr2;
            float c31 = (-L21 * c32 - L31 * c33) * r1;
            float c30 = (-L10 * c31 - L20 * c32 - L30 * c33) * r0;
            const float s01 = 0.5f * (c01 + c10), s02 = 0.5f * (c02 + c20);
            const float s03 = 0.5f * (c03 + c30), s12 = 0.5f * (c12 + c21);
            const float s13 = 0.5f * (c13 + c31), s23 = 0.5f * (c23 + c32);
            Si[0]  = c00; Si[1]  = s01; Si[2]  = s02; Si[3]  = s03;
            Si[4]  = s01; Si[5]  = c11; Si[6]  = s12; Si[7]  = s13;
            Si[8]  = s02; Si[9]  = s12; Si[10] = c22; Si[11] = s23;
            Si[12] = s03; Si[13] = s13; Si[14] = s23; Si[15] = c33;
        }

        // ===== S6: K = Pxy*Si, P_new, x_new, stores ==========================
        {
            const float4 pr = *(const float4*)&Pxy[k8 * 4];        // Pxy row k8
            float kk[4];
            #pragma unroll
            for (int aa = 0; aa < 4; ++aa)
                kk[aa] = pr.x * Si[0 * 4 + aa] + pr.y * Si[1 * 4 + aa]
                       + pr.z * Si[2 * 4 + aa] + pr.w * Si[3 * 4 + aa];
            if (g8 == 0) *(float4*)&K_s[k8 * 4] = make_float4(kk[0], kk[1], kk[2], kk[3]);
            float K_[32];
            #pragma unroll
            for (int r = 0; r < 8; ++r) {
                const float4 kr = *(const float4*)&K_s[r * 4];     // in-order
                K_[r * 4 + 0] = kr.x; K_[r * 4 + 1] = kr.y;
                K_[r * 4 + 2] = kr.z; K_[r * 4 + 3] = kr.w;
            }
            // P_new column k8 = Ppc - K * Pxy[k8,:]^T  (+ jitter). Ppc regs
            // survive into next iteration's deferred qe-LDL.
            #pragma unroll
            for (int i = 0; i < 8; ++i) {
                const float m = K_[i * 4 + 0] * pr.x + K_[i * 4 + 1] * pr.y
                              + K_[i * 4 + 2] * pr.z + K_[i * 4 + 3] * pr.w;
                Pc[i] = Ppc[i] - m + ((i == k8) ? 1e-4f : 0.0f);
            }
            const float4 yp = *(const float4*)&ypr[0];
            const float in0 = ytv.x - yp.x, in1 = ytv.y - yp.y;
            const float in2 = ytv.z - yp.z, in3 = ytv.w - yp.w;
            const float4 xpa = *(const float4*)&xp_[0];
            const float4 xpb = *(const float4*)&xp_[4];
            const float xpv[8] = {xpa.x, xpa.y, xpa.z, xpa.w, xpb.x, xpb.y, xpb.z, xpb.w};
            #pragma unroll
            for (int i = 0; i < 8; ++i)
                xn[i] = xpv[i] + K_[i * 4 + 0] * in0 + K_[i * 4 + 1] * in1
                               + K_[i * 4 + 2] * in2 + K_[i * 4 + 3] * in3;
            out[Pbase + (size_t)t * 64 + lane] = Pc[g8];
            if (lane == 0) {
                *(float4*)&out[Xbase + (size_t)t * 8]     = make_float4(xn[0], xn[1], xn[2], xn[3]);
                *(float4*)&out[Xbase + (size_t)t * 8 + 4] = make_float4(xn[4], xn[5], xn[6], xn[7]);
            }
        }
    }

    // final deferred qe for t = T_LEN-1
    {
        float qe = 0.0f;
        #pragma unroll
        for (int j = 0; j < 8; ++j) {
            const float dq = lane_bcast(Ppc[j], j);
            const float rq = fast_rcp(dq);
            qe += __logf(dq);
            const float tq = (k8 > j) ? Ppc[j] * rq : 0.0f;
            float uq[8];
            #pragma unroll
            for (int i = j + 1; i < 8; ++i) uq[i] = lane_bcast(Ppc[i], j);
            #pragma unroll
            for (int i = j + 1; i < 8; ++i) Ppc[i] = fmaf(-tq, uq[i], Ppc[i]);
        }
        if (lane == 0) out[qbase + (T_LEN - 1)] = 0.5f * qe;
    }
}

extern "C" void kernel_launch(void* const* d_in, const int* in_sizes, int n_in,
                              void* d_out, int out_size, void* d_ws, size_t ws_size,
                              hipStream_t stream) {
    (void)in_sizes; (void)n_in; (void)out_size; (void)d_ws; (void)ws_size;
    const float* X0 = (const float*)d_in[0];
    const float* U  = (const float*)d_in[1];
    const float* Y  = (const float*)d_in[2];
    const float* W1 = (const float*)d_in[3];
    const float* B1 = (const float*)d_in[4];
    const float* W2 = (const float*)d_in[5];
    const float* B2 = (const float*)d_in[6];
    const float* HM = (const float*)d_in[7];
    const float* LQ = (const float*)d_in[8];
    const float* LR = (const float*)d_in[9];
    const float* LP0 = (const float*)d_in[10];
    float* out = (float*)d_out;
    ukf_kernel<<<dim3(B_LEN / 8), dim3(512), 0, stream>>>(X0, U, Y, W1, B1, W2, B2,
                                                          HM, LQ, LR, LP0, out);
}

// Round 6
// 897.107 us; speedup vs baseline: 2.2430x; 1.4015x over previous
//
#include <hip/hip_runtime.h>
#include <math.h>

#define B_LEN 1024
#define T_LEN 256
#define HST 36   // hid_sh leading stride keeps float4 access conflict-light
#define TS 20    // dxT/ypT row stride (17 used + 3 pad): banks 20*r%32 distinct

__device__ __forceinline__ float fast_rcp(float x) { return __builtin_amdgcn_rcpf(x); }
__device__ __forceinline__ float fast_rsq(float x) { return __builtin_amdgcn_rsqf(x); }
__device__ __forceinline__ float lane_bcast(float v, int l) {
    return __int_as_float(__builtin_amdgcn_readlane(__float_as_int(v), l));
}
__device__ __forceinline__ float fast_tanh(float x) {
    float e = __expf(2.0f * x);
    return 1.0f - 2.0f * fast_rcp(e + 1.0f);
}
__device__ __forceinline__ float softplus_f(float x) {
    return (x > 20.0f) ? x : log1pf(expf(x));
}
// weighted 17-dot: 0.0625*sum(all 17) + (2-0.0625)*center  (Wc0=2, rest 1/16)
__device__ __forceinline__ float wdot17(const float* __restrict__ a,
                                        const float* __restrict__ b) {
    float full = 0.0f;
    #pragma unroll
    for (int c = 0; c < 4; ++c) {
        const float4 av = *(const float4*)&a[c * 4];
        const float4 bv = *(const float4*)&b[c * 4];
        full += av.x * bv.x + av.y * bv.y + av.z * bv.z + av.w * bv.w;
    }
    full += a[16] * b[16];
    return 0.0625f * full + 1.9375f * a[0] * b[0];
}

// One batch per 128-thread block (verified R0 structure, 891us; 2 waves,
// 8/CU -> 2 waves/SIMD chip-wide). Three verified local grafts only:
// (1) branchless column-chol8 (R2/R4-passed code) in phase A;
// (2) branchless qe-LDL (R2/R4-passed) in phase E [w1];
// (3) K broadcast via readlane instead of the K_sh LDS round-trip
//     (exact: lane r's kk[] IS K row r; K_sh deleted).
// Everything else byte-identical to the verified baseline.
__global__ __launch_bounds__(128, 2)
void ukf_kernel(const float* __restrict__ X0, const float* __restrict__ U,
                const float* __restrict__ Y,  const float* __restrict__ W1,
                const float* __restrict__ B1, const float* __restrict__ W2,
                const float* __restrict__ B2, const float* __restrict__ HM,
                const float* __restrict__ LQ, const float* __restrict__ LR,
                const float* __restrict__ LP0, float* __restrict__ out)
{
    const int tid  = threadIdx.x;
    const int wid  = tid >> 6;
    const int lane = tid & 63;
    const int b    = blockIdx.x;
    const int k8   = lane & 7;        // column / j8
    const int g8   = lane >> 3;       // replica group / i8
    const int i8   = g8;
    const int j8   = k8;
    const int h32  = lane & 31;
    const int p2   = lane >> 5;       // half-wave (L1 row parity)
    const int m4   = lane & 3;
    const int sy   = lane >> 2;

    __shared__ __align__(16) float u_sh[T_LEN * 2];
    __shared__ __align__(16) float y_sh[T_LEN * 4];
    __shared__ __align__(16) float pts_sh[17 * 8];
    __shared__ __align__(16) float hid_sh[17 * HST];
    __shared__ __align__(16) float pf_sh[17 * 8];
    __shared__ __align__(16) float dxT_sh[8 * TS];   // dxT[d][s]
    __shared__ __align__(16) float ypT_sh[4 * TS];   // ypT[m][s]
    __shared__ __align__(16) float xp_sh[8];
    __shared__ __align__(16) float ypred_sh[4];
    __shared__ __align__(16) float Sy_sh[16];
    __shared__ __align__(16) float Si_sh[16];
    __shared__ __align__(16) float Pxy_sh[32];
    __shared__ __align__(16) float Pp_sh[64];

    // ---- one-time staging ----
    for (int k = tid; k < T_LEN * 2; k += 128) u_sh[k] = U[(size_t)b * (T_LEN * 2) + k];
    for (int k = tid; k < T_LEN * 4; k += 128) y_sh[k] = Y[(size_t)b * (T_LEN * 4) + k];

    float w1r[10];
    #pragma unroll
    for (int d = 0; d < 10; ++d) w1r[d] = W1[d * 32 + h32];
    const float b1r = B1[h32];
    float w2r[32];
    #pragma unroll
    for (int h = 0; h < 32; ++h) w2r[h] = W2[h * 8 + k8];
    const float b2r = B2[k8];
    float hmr[8];                              // wave1 only
    #pragma unroll
    for (int d = 0; d < 8; ++d) hmr[d] = HM[m4 * 8 + d];

    const float qdiag = softplus_f(LQ[i8]);    // w0 (i8,j8) layout
    const float rdiag = softplus_f(LR[m4]);    // w1 Sy

    const size_t Xbase = (size_t)b * T_LEN * 8;
    const size_t Pbase = (size_t)B_LEN * T_LEN * 8  + (size_t)b * T_LEN * 64;
    const size_t qbase = (size_t)B_LEN * T_LEN * 72 + (size_t)b * T_LEN;
    const size_t rbase = (size_t)B_LEN * T_LEN * 73 + (size_t)b * T_LEN;

    // ---- persistent register state (w0): x replicated, P column k8 ----
    float xn[8], Pc[8];
    {
        const float4 xa = *(const float4*)&X0[b * 8];
        const float4 xb = *(const float4*)&X0[b * 8 + 4];
        xn[0] = xa.x; xn[1] = xa.y; xn[2] = xa.z; xn[3] = xa.w;
        xn[4] = xb.x; xn[5] = xb.y; xn[6] = xb.z; xn[7] = xb.w;
        const float p0k = softplus_f(LP0[k8]);
        #pragma unroll
        for (int i = 0; i < 8; ++i) Pc[i] = (i == k8) ? p0k : 0.0f;
    }
    if (wid == 0) {
        out[Pbase + lane] = Pc[g8];                  // coalesced 64-lane P store
        if (lane == 0) {
            *(float4*)&out[Xbase]     = make_float4(xn[0], xn[1], xn[2], xn[3]);
            *(float4*)&out[Xbase + 4] = make_float4(xn[4], xn[5], xn[6], xn[7]);
            out[qbase] = 0.0f; out[rbase] = 0.0f;
        }
    }

    for (int t = 1; t < T_LEN; ++t) {
        // ===== Phase A [w0]: branchless column-chol8 of 8P+jitter -> pts =====
        if (wid == 0) {
            float a[8];
            #pragma unroll
            for (int i = 0; i < 8; ++i) a[i] = 8.0f * Pc[i] + ((i == k8) ? 1e-4f : 0.0f);
            #pragma unroll
            for (int j = 0; j < 8; ++j) {
                const float dj = lane_bcast(a[j], j);
                const float rv = fast_rsq(dj);
                const float sc = (k8 == j) ? rv : 1.0f;
                const float tc = (k8 > j) ? a[j] * (rv * rv) : 0.0f;
                float u[8];
                #pragma unroll
                for (int i = j + 1; i < 8; ++i) u[i] = lane_bcast(a[i], j);
                #pragma unroll
                for (int i = j + 1; i < 8; ++i) a[i] = sc * a[i] - tc * u[i];
                a[j] = (k8 == j) ? dj * rv : a[j];
            }
            float Lc[8];
            #pragma unroll
            for (int i = 0; i < 8; ++i) Lc[i] = (i >= k8) ? a[i] : 0.0f;
            if (g8 == 0) {
                *(float4*)&pts_sh[(1 + k8) * 8] =
                    make_float4(xn[0] + Lc[0], xn[1] + Lc[1], xn[2] + Lc[2], xn[3] + Lc[3]);
                *(float4*)&pts_sh[(1 + k8) * 8 + 4] =
                    make_float4(xn[4] + Lc[4], xn[5] + Lc[5], xn[6] + Lc[6], xn[7] + Lc[7]);
            } else if (g8 == 1) {
                *(float4*)&pts_sh[(9 + k8) * 8] =
                    make_float4(xn[0] - Lc[0], xn[1] - Lc[1], xn[2] - Lc[2], xn[3] - Lc[3]);
                *(float4*)&pts_sh[(9 + k8) * 8 + 4] =
                    make_float4(xn[4] - Lc[4], xn[5] - Lc[5], xn[6] - Lc[6], xn[7] - Lc[7]);
            } else if (g8 == 2 && k8 == 0) {
                *(float4*)&pts_sh[0] = make_float4(xn[0], xn[1], xn[2], xn[3]);
                *(float4*)&pts_sh[4] = make_float4(xn[4], xn[5], xn[6], xn[7]);
            }
        }
        __syncthreads();   // b1: pts ready

        // ===== Phase B [both]: fused L1+L2, per-wave sigma sets ===============
        {
            const float u0 = u_sh[(t - 1) * 2 + 0];
            const float u1 = u_sh[(t - 1) * 2 + 1];
            const float ub = b1r + u0 * w1r[8] + u1 * w1r[9];
            if (wid == 0) {
                #pragma unroll
                for (int p = 0; p < 4; ++p) {
                    const int s = 2 * p + p2;                 // rows 0..7
                    const float4 pa = *(const float4*)&pts_sh[s * 8];
                    const float4 pb = *(const float4*)&pts_sh[s * 8 + 4];
                    float acc = ub
                        + pa.x * w1r[0] + pa.y * w1r[1] + pa.z * w1r[2] + pa.w * w1r[3]
                        + pb.x * w1r[4] + pb.y * w1r[5] + pb.z * w1r[6] + pb.w * w1r[7];
                    hid_sh[s * HST + h32] = fast_tanh(acc);
                }
            } else {
                #pragma unroll
                for (int p = 0; p < 4; ++p) {
                    const int s = 8 + 2 * p + p2;             // rows 8..15
                    const float4 pa = *(const float4*)&pts_sh[s * 8];
                    const float4 pb = *(const float4*)&pts_sh[s * 8 + 4];
                    float acc = ub
                        + pa.x * w1r[0] + pa.y * w1r[1] + pa.z * w1r[2] + pa.w * w1r[3]
                        + pb.x * w1r[4] + pb.y * w1r[5] + pb.z * w1r[6] + pb.w * w1r[7];
                    hid_sh[s * HST + h32] = fast_tanh(acc);
                }
                if (p2 == 0) {                                // row 16
                    const float4 pa = *(const float4*)&pts_sh[16 * 8];
                    const float4 pb = *(const float4*)&pts_sh[16 * 8 + 4];
                    float acc = ub
                        + pa.x * w1r[0] + pa.y * w1r[1] + pa.z * w1r[2] + pa.w * w1r[3]
                        + pb.x * w1r[4] + pb.y * w1r[5] + pb.z * w1r[6] + pb.w * w1r[7];
                    hid_sh[16 * HST + h32] = fast_tanh(acc);
                }
            }
            // L2 on own-wave rows (same-wave DS in-order: no barrier)
            const int srow = (wid == 0) ? g8 : (8 + g8);
            float acc = b2r;
            #pragma unroll
            for (int h = 0; h < 32; h += 4) {
                const float4 hv = *(const float4*)&hid_sh[srow * HST + h];
                acc += hv.x * w2r[h] + hv.y * w2r[h + 1] + hv.z * w2r[h + 2] + hv.w * w2r[h + 3];
            }
            pf_sh[srow * 8 + k8] = pts_sh[srow * 8 + k8] + acc;
            if (wid == 1 && lane < 8) {
                float a16 = b2r;
                #pragma unroll
                for (int h = 0; h < 32; h += 4) {
                    const float4 hv = *(const float4*)&hid_sh[16 * HST + h];
                    a16 += hv.x * w2r[h] + hv.y * w2r[h + 1] + hv.z * w2r[h + 2] + hv.w * w2r[h + 3];
                }
                pf_sh[16 * 8 + lane] = pts_sh[16 * 8 + lane] + a16;
            }
        }
        __syncthreads();   // b2: pf ready

        // ===== Phase C [w0]: x_pred + dxT ; [w1]: y_pts + ypred + ypT =========
        if (wid == 0) {
            const float v0   = pf_sh[i8 * 8 + j8];
            const float v1   = pf_sh[(8 + i8) * 8 + j8];
            const float pf16 = (i8 == 0) ? pf_sh[16 * 8 + j8] : 0.0f;
            float part = ((i8 == 0) ? pf16 : v0) + v1;        // s=16 replaces s=0
            part += __shfl_xor(part, 8);
            part += __shfl_xor(part, 16);
            part += __shfl_xor(part, 32);
            const float xp = part * 0.0625f;
            if (i8 == 0) xp_sh[j8] = xp;
            dxT_sh[j8 * TS + i8]       = v0 - xp;             // dxT[d][s]
            dxT_sh[j8 * TS + 8 + i8]   = v1 - xp;
            if (i8 == 0) dxT_sh[j8 * TS + 16] = pf16 - xp;
        } else {
            float yv0, yv16 = 0.0f;
            {
                const float4 pa = *(const float4*)&pf_sh[sy * 8];
                const float4 pb = *(const float4*)&pf_sh[sy * 8 + 4];
                yv0 = pa.x * hmr[0] + pa.y * hmr[1] + pa.z * hmr[2] + pa.w * hmr[3]
                    + pb.x * hmr[4] + pb.y * hmr[5] + pb.z * hmr[6] + pb.w * hmr[7];
            }
            if (sy == 0) {
                const float4 pa = *(const float4*)&pf_sh[16 * 8];
                const float4 pb = *(const float4*)&pf_sh[16 * 8 + 4];
                yv16 = pa.x * hmr[0] + pa.y * hmr[1] + pa.z * hmr[2] + pa.w * hmr[3]
                     + pb.x * hmr[4] + pb.y * hmr[5] + pb.z * hmr[6] + pb.w * hmr[7];
            }
            float py = (sy == 0) ? yv16 : yv0;
            py += __shfl_xor(py, 4);
            py += __shfl_xor(py, 8);
            py += __shfl_xor(py, 16);
            py += __shfl_xor(py, 32);
            const float ypred = py * 0.0625f;
            if (lane < 4) ypred_sh[lane] = ypred;
            ypT_sh[m4 * TS + sy] = yv0 - ypred;               // ypT[m][s]
            if (sy == 0) ypT_sh[m4 * TS + 16] = yv16 - ypred;
        }
        __syncthreads();   // b3: dxT, ypT, xp, ypred ready

        // ===== Phase D: [w0] Ppred + Pxy ; [w1] Sy -> chol4 -> Sy^-1 + re =====
        float Ppc[8];
        if (wid == 0) {
            const float Ppred = wdot17(&dxT_sh[i8 * TS], &dxT_sh[j8 * TS])
                              + ((i8 == j8) ? (qdiag + 1e-4f) : 0.0f);
            Pp_sh[lane] = Ppred;
            if (lane < 32) {
                const int ii = lane >> 2, mm = lane & 3;
                Pxy_sh[lane] = wdot17(&dxT_sh[ii * TS], &ypT_sh[mm * TS]);
            }
            #pragma unroll
            for (int i = 0; i < 8; ++i) Ppc[i] = Pp_sh[i * 8 + k8];   // in-wave
        } else {
            if (lane < 16)
                Sy_sh[lane] = wdot17(&ypT_sh[sy * TS], &ypT_sh[m4 * TS])
                            + ((sy == m4) ? rdiag : 0.0f);
            // in-wave readback (same-wave DS in-order), replicated chol4
            float s_[16];
            {
                const float4 r0v = *(const float4*)&Sy_sh[0];
                const float4 r1v = *(const float4*)&Sy_sh[4];
                const float4 r2v = *(const float4*)&Sy_sh[8];
                const float4 r3v = *(const float4*)&Sy_sh[12];
                s_[0]=r0v.x;  s_[1]=r0v.y;  s_[2]=r0v.z;  s_[3]=r0v.w;
                s_[4]=r1v.x;  s_[5]=r1v.y;  s_[6]=r1v.z;  s_[7]=r1v.w;
                s_[8]=r2v.x;  s_[9]=r2v.y;  s_[10]=r2v.z; s_[11]=r2v.w;
                s_[12]=r3v.x; s_[13]=r3v.y; s_[14]=r3v.z; s_[15]=r3v.w;
            }
            const float d0 = s_[0];
            const float r0 = fast_rsq(d0);
            const float L10 = s_[4] * r0, L20 = s_[8] * r0, L30 = s_[12] * r0;
            const float d1 = s_[5] - L10 * L10;
            const float r1 = fast_rsq(d1);
            const float L21 = (s_[9]  - L20 * L10) * r1;
            const float L31 = (s_[13] - L30 * L10) * r1;
            const float d2_ = s_[10] - L20 * L20 - L21 * L21;
            const float r2 = fast_rsq(d2_);
            const float L32 = (s_[14] - L30 * L20 - L31 * L21) * r2;
            const float d3 = s_[15] - L30 * L30 - L31 * L31 - L32 * L32;
            const float r3 = fast_rsq(d3);
            if (lane == 0)
                out[rbase + t] = 0.5f * (__logf(d0) + __logf(d1) + __logf(d2_) + __logf(d3));
            // explicit Sy^{-1} = L^{-T} L^{-1}, column by column, symmetrized
            float z1 = -L10 * r0 * r1;
            float z2 = -(L20 * r0 + L21 * z1) * r2;
            float z3 = -(L30 * r0 + L31 * z1 + L32 * z2) * r3;
            float c03 = z3 * r3;
            float c02 = (z2 - L32 * c03) * r2;
            float c01 = (z1 - L21 * c02 - L31 * c03) * r1;
            float c00 = (r0 - L10 * c01 - L20 * c02 - L30 * c03) * r0;
            float z2b = -L21 * r1 * r2;
            float z3b = -(L31 * r1 + L32 * z2b) * r3;
            float c13 = z3b * r3;
            float c12 = (z2b - L32 * c13) * r2;
            float c11 = (r1 - L21 * c12 - L31 * c13) * r1;
            float c10 = (-L10 * c11 - L20 * c12 - L30 * c13) * r0;
            float z3c = -L32 * r2 * r3;
            float c23 = z3c * r3;
            float c22 = (r2 - L32 * c23) * r2;
            float c21 = (-L21 * c22 - L31 * c23) * r1;
            float c20 = (-L10 * c21 - L20 * c22 - L30 * c23) * r0;
            float c33 = r3 * r3;
            float c32 = (-L32 * c33) * r2;
            float c31 = (-L21 * c32 - L31 * c33) * r1;
            float c30 = (-L10 * c31 - L20 * c32 - L30 * c33) * r0;
            const float s01 = 0.5f * (c01 + c10), s02 = 0.5f * (c02 + c20);
            const float s03 = 0.5f * (c03 + c30), s12 = 0.5f * (c12 + c21);
            const float s13 = 0.5f * (c13 + c31), s23 = 0.5f * (c23 + c32);
            if (lane == 0) {
                *(float4*)&Si_sh[0]  = make_float4(c00, s01, s02, s03);
                *(float4*)&Si_sh[4]  = make_float4(s01, c11, s12, s13);
                *(float4*)&Si_sh[8]  = make_float4(s02, s12, c22, s23);
                *(float4*)&Si_sh[12] = make_float4(s03, s13, s23, c33);
            }
        }
        __syncthreads();   // b4: Pp / Si / Pxy ready

        // ===== Phase E: [w0] K = Pxy Si (readlane bcast), P_new, x_new ; [w1] qe
        if (wid == 0) {
            float Si[16];
            {
                const float4 a0 = *(const float4*)&Si_sh[0];
                const float4 a1 = *(const float4*)&Si_sh[4];
                const float4 a2 = *(const float4*)&Si_sh[8];
                const float4 a3 = *(const float4*)&Si_sh[12];
                Si[0]=a0.x;  Si[1]=a0.y;  Si[2]=a0.z;  Si[3]=a0.w;
                Si[4]=a1.x;  Si[5]=a1.y;  Si[6]=a1.z;  Si[7]=a1.w;
                Si[8]=a2.x;  Si[9]=a2.y;  Si[10]=a2.z; Si[11]=a2.w;
                Si[12]=a3.x; Si[13]=a3.y; Si[14]=a3.z; Si[15]=a3.w;
            }
            const float4 pr = *(const float4*)&Pxy_sh[k8 * 4];     // Pxy row k8
            float kk[4];
            #pragma unroll
            for (int aa = 0; aa < 4; ++aa)
                kk[aa] = pr.x * Si[0 * 4 + aa] + pr.y * Si[1 * 4 + aa]
                       + pr.z * Si[2 * 4 + aa] + pr.w * Si[3 * 4 + aa];
            // K broadcast via readlane: lane r (r<8) holds K row r in kk[]
            float K_[32];
            #pragma unroll
            for (int r = 0; r < 8; ++r) {
                K_[r * 4 + 0] = lane_bcast(kk[0], r);
                K_[r * 4 + 1] = lane_bcast(kk[1], r);
                K_[r * 4 + 2] = lane_bcast(kk[2], r);
                K_[r * 4 + 3] = lane_bcast(kk[3], r);
            }
            // P_new column k8 = Ppc - K * Pxy[k8,:]^T  (+ jitter)
            #pragma unroll
            for (int i = 0; i < 8; ++i) {
                const float m = K_[i * 4 + 0] * pr.x + K_[i * 4 + 1] * pr.y
                              + K_[i * 4 + 2] * pr.z + K_[i * 4 + 3] * pr.w;
                Pc[i] = Ppc[i] - m + ((i == k8) ? 1e-4f : 0.0f);
            }
            // x_new (replicated)
            const float4 yt = *(const float4*)&y_sh[t * 4];
            const float4 yp = *(const float4*)&ypred_sh[0];
            const float in0 = yt.x - yp.x, in1 = yt.y - yp.y;
            const float in2 = yt.z - yp.z, in3 = yt.w - yp.w;
            const float4 xpa = *(const float4*)&xp_sh[0];
            const float4 xpb = *(const float4*)&xp_sh[4];
            const float xpv[8] = {xpa.x, xpa.y, xpa.z, xpa.w, xpb.x, xpb.y, xpb.z, xpb.w};
            #pragma unroll
            for (int i = 0; i < 8; ++i)
                xn[i] = xpv[i] + K_[i * 4 + 0] * in0 + K_[i * 4 + 1] * in1
                               + K_[i * 4 + 2] * in2 + K_[i * 4 + 3] * in3;
            // stores: coalesced 64-lane P store (lane (g8,k8) owns P[g8][k8])
            out[Pbase + (size_t)t * 64 + lane] = Pc[g8];
            if (lane == 0) {
                *(float4*)&out[Xbase + (size_t)t * 8]     = make_float4(xn[0], xn[1], xn[2], xn[3]);
                *(float4*)&out[Xbase + (size_t)t * 8 + 4] = make_float4(xn[4], xn[5], xn[6], xn[7]);
            }
        } else {
            // qe = 0.5 slogdet(P_pred): branchless column LDL, diag-only
            float aq[8];
            #pragma unroll
            for (int i = 0; i < 8; ++i) aq[i] = Pp_sh[i * 8 + k8];
            float qe = 0.0f;
            #pragma unroll
            for (int j = 0; j < 8; ++j) {
                const float dj  = lane_bcast(aq[j], j);
                qe += __logf(dj);
                const float rv2 = fast_rcp(dj);
                const float tq  = (k8 > j) ? aq[j] * rv2 : 0.0f;
                float u[8];
                #pragma unroll
                for (int i = j + 1; i < 8; ++i) u[i] = lane_bcast(aq[i], j);
                #pragma unroll
                for (int i = j + 1; i < 8; ++i) aq[i] = fmaf(-tq, u[i], aq[i]);
            }
            if (lane == 0) out[qbase + t] = 0.5f * qe;
        }
        // no trailing barrier: next-step hazards are covered by b1..b4 ordering
    }
}

extern "C" void kernel_launch(void* const* d_in, const int* in_sizes, int n_in,
                              void* d_out, int out_size, void* d_ws, size_t ws_size,
                              hipStream_t stream) {
    (void)in_sizes; (void)n_in; (void)out_size; (void)d_ws; (void)ws_size;
    const float* X0 = (const float*)d_in[0];
    const float* U  = (const float*)d_in[1];
    const float* Y  = (const float*)d_in[2];
    const float* W1 = (const float*)d_in[3];
    const float* B1 = (const float*)d_in[4];
    const float* W2 = (const float*)d_in[5];
    const float* B2 = (const float*)d_in[6];
    const float* HM = (const float*)d_in[7];
    const float* LQ = (const float*)d_in[8];
    const float* LR = (const float*)d_in[9];
    const float* LP0 = (const float*)d_in[10];
    float* out = (float*)d_out;
    ukf_kernel<<<dim3(B_LEN), dim3(128), 0, stream>>>(X0, U, Y, W1, B1, W2, B2,
                                                      HM, LQ, LR, LP0, out);
}

// Round 7
// 832.324 us; speedup vs baseline: 2.4176x; 1.0778x over previous
//
#include <hip/hip_runtime.h>
#include <math.h>

#define B_LEN 1024
#define T_LEN 256
#define HST 36   // hid_sh leading stride keeps float4 access conflict-light
#define TS 20    // dxT/ypT row stride (17 used + 3 pad): banks 20*r%32 distinct

__device__ __forceinline__ float fast_rcp(float x) { return __builtin_amdgcn_rcpf(x); }
__device__ __forceinline__ float fast_rsq(float x) { return __builtin_amdgcn_rsqf(x); }
__device__ __forceinline__ float lane_bcast(float v, int l) {
    return __int_as_float(__builtin_amdgcn_readlane(__float_as_int(v), l));
}
__device__ __forceinline__ float fast_tanh(float x) {
    float e = __expf(2.0f * x);
    return 1.0f - 2.0f * fast_rcp(e + 1.0f);
}
__device__ __forceinline__ float softplus_f(float x) {
    return (x > 20.0f) ? x : log1pf(expf(x));
}
// weighted 17-dot: 0.0625*sum(all 17) + (2-0.0625)*center  (Wc0=2, rest 1/16)
__device__ __forceinline__ float wdot17(const float* __restrict__ a,
                                        const float* __restrict__ b) {
    float full = 0.0f;
    #pragma unroll
    for (int c = 0; c < 4; ++c) {
        const float4 av = *(const float4*)&a[c * 4];
        const float4 bv = *(const float4*)&b[c * 4];
        full += av.x * bv.x + av.y * bv.y + av.z * bv.z + av.w * bv.w;
    }
    full += a[16] * b[16];
    return 0.0625f * full + 1.9375f * a[0] * b[0];
}

// R6 verified base (876us) + three local pole-shortening deltas:
// (D1) w1 phase D: chol4+serial-inverse replaced by PARALLEL 4x4 cofactor
//      inverse (16 lanes x one 3x3 det each; det via Laplace row 0; Si=C/det,
//      C symmetric for symmetric Sy); r_e = 0.5*log(det) -- 1 log not 4.
// (D2) w0 phase E: symmetric P_new -- K*Pxy^T = K*Sy*K^T is symmetric, so
//      Pc[i] = Ppc[i] - dot(kk_own, Pxy row i): 8 broadcast LDS reads of Pxy
//      rows replace the 32-readlane K broadcast.
// (D3) w0 phase E: x_new own-row (xo = xp[k8] + kk.in) then 8 readlanes.
// Barriers and all other phases byte-identical to the verified base.
__global__ __launch_bounds__(128, 2)
void ukf_kernel(const float* __restrict__ X0, const float* __restrict__ U,
                const float* __restrict__ Y,  const float* __restrict__ W1,
                const float* __restrict__ B1, const float* __restrict__ W2,
                const float* __restrict__ B2, const float* __restrict__ HM,
                const float* __restrict__ LQ, const float* __restrict__ LR,
                const float* __restrict__ LP0, float* __restrict__ out)
{
    const int tid  = threadIdx.x;
    const int wid  = tid >> 6;
    const int lane = tid & 63;
    const int b    = blockIdx.x;
    const int k8   = lane & 7;        // column / j8
    const int g8   = lane >> 3;       // replica group / i8
    const int i8   = g8;
    const int j8   = k8;
    const int h32  = lane & 31;
    const int p2   = lane >> 5;       // half-wave (L1 row parity)
    const int m4   = lane & 3;
    const int sy   = lane >> 2;

    __shared__ __align__(16) float u_sh[T_LEN * 2];
    __shared__ __align__(16) float y_sh[T_LEN * 4];
    __shared__ __align__(16) float pts_sh[17 * 8];
    __shared__ __align__(16) float hid_sh[17 * HST];
    __shared__ __align__(16) float pf_sh[17 * 8];
    __shared__ __align__(16) float dxT_sh[8 * TS];   // dxT[d][s]
    __shared__ __align__(16) float ypT_sh[4 * TS];   // ypT[m][s]
    __shared__ __align__(16) float xp_sh[8];
    __shared__ __align__(16) float ypred_sh[4];
    __shared__ __align__(16) float Sy_sh[16];
    __shared__ __align__(16) float Si_sh[16];
    __shared__ __align__(16) float Pxy_sh[32];
    __shared__ __align__(16) float Pp_sh[64];

    // ---- one-time staging ----
    for (int k = tid; k < T_LEN * 2; k += 128) u_sh[k] = U[(size_t)b * (T_LEN * 2) + k];
    for (int k = tid; k < T_LEN * 4; k += 128) y_sh[k] = Y[(size_t)b * (T_LEN * 4) + k];

    float w1r[10];
    #pragma unroll
    for (int d = 0; d < 10; ++d) w1r[d] = W1[d * 32 + h32];
    const float b1r = B1[h32];
    float w2r[32];
    #pragma unroll
    for (int h = 0; h < 32; ++h) w2r[h] = W2[h * 8 + k8];
    const float b2r = B2[k8];
    float hmr[8];                              // wave1 only
    #pragma unroll
    for (int d = 0; d < 8; ++d) hmr[d] = HM[m4 * 8 + d];

    const float qdiag = softplus_f(LQ[i8]);    // w0 (i8,j8) layout
    const float rdiag = softplus_f(LR[m4]);    // w1 Sy

    const size_t Xbase = (size_t)b * T_LEN * 8;
    const size_t Pbase = (size_t)B_LEN * T_LEN * 8  + (size_t)b * T_LEN * 64;
    const size_t qbase = (size_t)B_LEN * T_LEN * 72 + (size_t)b * T_LEN;
    const size_t rbase = (size_t)B_LEN * T_LEN * 73 + (size_t)b * T_LEN;

    // ---- persistent register state (w0): x replicated, P column k8 ----
    float xn[8], Pc[8];
    {
        const float4 xa = *(const float4*)&X0[b * 8];
        const float4 xb = *(const float4*)&X0[b * 8 + 4];
        xn[0] = xa.x; xn[1] = xa.y; xn[2] = xa.z; xn[3] = xa.w;
        xn[4] = xb.x; xn[5] = xb.y; xn[6] = xb.z; xn[7] = xb.w;
        const float p0k = softplus_f(LP0[k8]);
        #pragma unroll
        for (int i = 0; i < 8; ++i) Pc[i] = (i == k8) ? p0k : 0.0f;
    }
    if (wid == 0) {
        out[Pbase + lane] = Pc[g8];                  // coalesced 64-lane P store
        if (lane == 0) {
            *(float4*)&out[Xbase]     = make_float4(xn[0], xn[1], xn[2], xn[3]);
            *(float4*)&out[Xbase + 4] = make_float4(xn[4], xn[5], xn[6], xn[7]);
            out[qbase] = 0.0f; out[rbase] = 0.0f;
        }
    }

    for (int t = 1; t < T_LEN; ++t) {
        // ===== Phase A [w0]: branchless column-chol8 of 8P+jitter -> pts =====
        if (wid == 0) {
            float a[8];
            #pragma unroll
            for (int i = 0; i < 8; ++i) a[i] = 8.0f * Pc[i] + ((i == k8) ? 1e-4f : 0.0f);
            #pragma unroll
            for (int j = 0; j < 8; ++j) {
                const float dj = lane_bcast(a[j], j);
                const float rv = fast_rsq(dj);
                const float sc = (k8 == j) ? rv : 1.0f;
                const float tc = (k8 > j) ? a[j] * (rv * rv) : 0.0f;
                float u[8];
                #pragma unroll
                for (int i = j + 1; i < 8; ++i) u[i] = lane_bcast(a[i], j);
                #pragma unroll
                for (int i = j + 1; i < 8; ++i) a[i] = sc * a[i] - tc * u[i];
                a[j] = (k8 == j) ? dj * rv : a[j];
            }
            float Lc[8];
            #pragma unroll
            for (int i = 0; i < 8; ++i) Lc[i] = (i >= k8) ? a[i] : 0.0f;
            if (g8 == 0) {
                *(float4*)&pts_sh[(1 + k8) * 8] =
                    make_float4(xn[0] + Lc[0], xn[1] + Lc[1], xn[2] + Lc[2], xn[3] + Lc[3]);
                *(float4*)&pts_sh[(1 + k8) * 8 + 4] =
                    make_float4(xn[4] + Lc[4], xn[5] + Lc[5], xn[6] + Lc[6], xn[7] + Lc[7]);
            } else if (g8 == 1) {
                *(float4*)&pts_sh[(9 + k8) * 8] =
                    make_float4(xn[0] - Lc[0], xn[1] - Lc[1], xn[2] - Lc[2], xn[3] - Lc[3]);
                *(float4*)&pts_sh[(9 + k8) * 8 + 4] =
                    make_float4(xn[4] - Lc[4], xn[5] - Lc[5], xn[6] - Lc[6], xn[7] - Lc[7]);
            } else if (g8 == 2 && k8 == 0) {
                *(float4*)&pts_sh[0] = make_float4(xn[0], xn[1], xn[2], xn[3]);
                *(float4*)&pts_sh[4] = make_float4(xn[4], xn[5], xn[6], xn[7]);
            }
        }
        __syncthreads();   // b1: pts ready

        // ===== Phase B [both]: fused L1+L2, per-wave sigma sets ===============
        {
            const float u0 = u_sh[(t - 1) * 2 + 0];
            const float u1 = u_sh[(t - 1) * 2 + 1];
            const float ub = b1r + u0 * w1r[8] + u1 * w1r[9];
            if (wid == 0) {
                #pragma unroll
                for (int p = 0; p < 4; ++p) {
                    const int s = 2 * p + p2;                 // rows 0..7
                    const float4 pa = *(const float4*)&pts_sh[s * 8];
                    const float4 pb = *(const float4*)&pts_sh[s * 8 + 4];
                    float acc = ub
                        + pa.x * w1r[0] + pa.y * w1r[1] + pa.z * w1r[2] + pa.w * w1r[3]
                        + pb.x * w1r[4] + pb.y * w1r[5] + pb.z * w1r[6] + pb.w * w1r[7];
                    hid_sh[s * HST + h32] = fast_tanh(acc);
                }
            } else {
                #pragma unroll
                for (int p = 0; p < 4; ++p) {
                    const int s = 8 + 2 * p + p2;             // rows 8..15
                    const float4 pa = *(const float4*)&pts_sh[s * 8];
                    const float4 pb = *(const float4*)&pts_sh[s * 8 + 4];
                    float acc = ub
                        + pa.x * w1r[0] + pa.y * w1r[1] + pa.z * w1r[2] + pa.w * w1r[3]
                        + pb.x * w1r[4] + pb.y * w1r[5] + pb.z * w1r[6] + pb.w * w1r[7];
                    hid_sh[s * HST + h32] = fast_tanh(acc);
                }
                if (p2 == 0) {                                // row 16
                    const float4 pa = *(const float4*)&pts_sh[16 * 8];
                    const float4 pb = *(const float4*)&pts_sh[16 * 8 + 4];
                    float acc = ub
                        + pa.x * w1r[0] + pa.y * w1r[1] + pa.z * w1r[2] + pa.w * w1r[3]
                        + pb.x * w1r[4] + pb.y * w1r[5] + pb.z * w1r[6] + pb.w * w1r[7];
                    hid_sh[16 * HST + h32] = fast_tanh(acc);
                }
            }
            // L2 on own-wave rows (same-wave DS in-order: no barrier)
            const int srow = (wid == 0) ? g8 : (8 + g8);
            float acc = b2r;
            #pragma unroll
            for (int h = 0; h < 32; h += 4) {
                const float4 hv = *(const float4*)&hid_sh[srow * HST + h];
                acc += hv.x * w2r[h] + hv.y * w2r[h + 1] + hv.z * w2r[h + 2] + hv.w * w2r[h + 3];
            }
            pf_sh[srow * 8 + k8] = pts_sh[srow * 8 + k8] + acc;
            if (wid == 1 && lane < 8) {
                float a16 = b2r;
                #pragma unroll
                for (int h = 0; h < 32; h += 4) {
                    const float4 hv = *(const float4*)&hid_sh[16 * HST + h];
                    a16 += hv.x * w2r[h] + hv.y * w2r[h + 1] + hv.z * w2r[h + 2] + hv.w * w2r[h + 3];
                }
                pf_sh[16 * 8 + lane] = pts_sh[16 * 8 + lane] + a16;
            }
        }
        __syncthreads();   // b2: pf ready

        // ===== Phase C [w0]: x_pred + dxT ; [w1]: y_pts + ypred + ypT =========
        if (wid == 0) {
            const float v0   = pf_sh[i8 * 8 + j8];
            const float v1   = pf_sh[(8 + i8) * 8 + j8];
            const float pf16 = (i8 == 0) ? pf_sh[16 * 8 + j8] : 0.0f;
            float part = ((i8 == 0) ? pf16 : v0) + v1;        // s=16 replaces s=0
            part += __shfl_xor(part, 8);
            part += __shfl_xor(part, 16);
            part += __shfl_xor(part, 32);
            const float xp = part * 0.0625f;
            if (i8 == 0) xp_sh[j8] = xp;
            dxT_sh[j8 * TS + i8]       = v0 - xp;             // dxT[d][s]
            dxT_sh[j8 * TS + 8 + i8]   = v1 - xp;
            if (i8 == 0) dxT_sh[j8 * TS + 16] = pf16 - xp;
        } else {
            float yv0, yv16 = 0.0f;
            {
                const float4 pa = *(const float4*)&pf_sh[sy * 8];
                const float4 pb = *(const float4*)&pf_sh[sy * 8 + 4];
                yv0 = pa.x * hmr[0] + pa.y * hmr[1] + pa.z * hmr[2] + pa.w * hmr[3]
                    + pb.x * hmr[4] + pb.y * hmr[5] + pb.z * hmr[6] + pb.w * hmr[7];
            }
            if (sy == 0) {
                const float4 pa = *(const float4*)&pf_sh[16 * 8];
                const float4 pb = *(const float4*)&pf_sh[16 * 8 + 4];
                yv16 = pa.x * hmr[0] + pa.y * hmr[1] + pa.z * hmr[2] + pa.w * hmr[3]
                     + pb.x * hmr[4] + pb.y * hmr[5] + pb.z * hmr[6] + pb.w * hmr[7];
            }
            float py = (sy == 0) ? yv16 : yv0;
            py += __shfl_xor(py, 4);
            py += __shfl_xor(py, 8);
            py += __shfl_xor(py, 16);
            py += __shfl_xor(py, 32);
            const float ypred = py * 0.0625f;
            if (lane < 4) ypred_sh[lane] = ypred;
            ypT_sh[m4 * TS + sy] = yv0 - ypred;               // ypT[m][s]
            if (sy == 0) ypT_sh[m4 * TS + 16] = yv16 - ypred;
        }
        __syncthreads();   // b3: dxT, ypT, xp, ypred ready

        // ===== Phase D: [w0] Ppred + Pxy ; [w1] Sy -> parallel cofactor Si ====
        float Ppc[8];
        if (wid == 0) {
            const float Ppred = wdot17(&dxT_sh[i8 * TS], &dxT_sh[j8 * TS])
                              + ((i8 == j8) ? (qdiag + 1e-4f) : 0.0f);
            Pp_sh[lane] = Ppred;
            if (lane < 32) {
                const int ii = lane >> 2, mm = lane & 3;
                Pxy_sh[lane] = wdot17(&dxT_sh[ii * TS], &ypT_sh[mm * TS]);
            }
            #pragma unroll
            for (int i = 0; i < 8; ++i) Ppc[i] = Pp_sh[i * 8 + k8];   // in-wave
        } else {
            if (lane < 16)
                Sy_sh[lane] = wdot17(&ypT_sh[sy * TS], &ypT_sh[m4 * TS])
                            + ((sy == m4) ? rdiag : 0.0f);
            // parallel 4x4 cofactor inverse: lane (i4,j4) computes cofactor
            // C[i4][j4] (3x3 det); det via Laplace row 0 (cof(0,a) in lane a);
            // Si = C/det (C symmetric for symmetric Sy). Single-log r_e.
            float cof;
            {
                const int i4 = sy & 3;            // lanes<16: sy = row index
                const int j4 = m4;                // col index
                const int r0 = (i4 == 0) ? 1 : 0;
                const int r1 = (i4 <= 1) ? 2 : 1;
                const int r2 = (i4 <= 2) ? 3 : 2;
                const int c0 = (j4 == 0) ? 1 : 0;
                const int c1 = (j4 <= 1) ? 2 : 1;
                const int c2 = (j4 <= 2) ? 3 : 2;
                const float m00 = Sy_sh[r0 * 4 + c0], m01 = Sy_sh[r0 * 4 + c1], m02 = Sy_sh[r0 * 4 + c2];
                const float m10 = Sy_sh[r1 * 4 + c0], m11 = Sy_sh[r1 * 4 + c1], m12 = Sy_sh[r1 * 4 + c2];
                const float m20 = Sy_sh[r2 * 4 + c0], m21 = Sy_sh[r2 * 4 + c1], m22 = Sy_sh[r2 * 4 + c2];
                const float d3 = m00 * (m11 * m22 - m12 * m21)
                               - m01 * (m10 * m22 - m12 * m20)
                               + m02 * (m10 * m21 - m11 * m20);
                cof = (((i4 + j4) & 1) ? -d3 : d3);
            }
            const float c0b = lane_bcast(cof, 0);
            const float c1b = lane_bcast(cof, 1);
            const float c2b = lane_bcast(cof, 2);
            const float c3b = lane_bcast(cof, 3);
            const float4 sy0 = *(const float4*)&Sy_sh[0];
            const float det = sy0.x * c0b + sy0.y * c1b + sy0.z * c2b + sy0.w * c3b;
            if (lane == 0) out[rbase + t] = 0.5f * __logf(det);
            const float rdet = fast_rcp(det);
            if (lane < 16) Si_sh[lane] = cof * rdet;
        }
        __syncthreads();   // b4: Pp / Si / Pxy ready

        // ===== Phase E: [w0] kk -> P_new(symmetric form), x_new ; [w1] qe =====
        if (wid == 0) {
            float Si[16];
            {
                const float4 a0 = *(const float4*)&Si_sh[0];
                const float4 a1 = *(const float4*)&Si_sh[4];
                const float4 a2 = *(const float4*)&Si_sh[8];
                const float4 a3 = *(const float4*)&Si_sh[12];
                Si[0]=a0.x;  Si[1]=a0.y;  Si[2]=a0.z;  Si[3]=a0.w;
                Si[4]=a1.x;  Si[5]=a1.y;  Si[6]=a1.z;  Si[7]=a1.w;
                Si[8]=a2.x;  Si[9]=a2.y;  Si[10]=a2.z; Si[11]=a2.w;
                Si[12]=a3.x; Si[13]=a3.y; Si[14]=a3.z; Si[15]=a3.w;
            }
            const float4 pr = *(const float4*)&Pxy_sh[k8 * 4];     // Pxy row k8
            float kk[4];
            #pragma unroll
            for (int aa = 0; aa < 4; ++aa)
                kk[aa] = pr.x * Si[0 * 4 + aa] + pr.y * Si[1 * 4 + aa]
                       + pr.z * Si[2 * 4 + aa] + pr.w * Si[3 * 4 + aa];
            // all 8 Pxy rows (broadcast LDS reads, compile-time indexed regs)
            float Pr[32];
            {
                const float4 q0 = *(const float4*)&Pxy_sh[0];
                const float4 q1 = *(const float4*)&Pxy_sh[4];
                const float4 q2 = *(const float4*)&Pxy_sh[8];
                const float4 q3 = *(const float4*)&Pxy_sh[12];
                const float4 q4 = *(const float4*)&Pxy_sh[16];
                const float4 q5 = *(const float4*)&Pxy_sh[20];
                const float4 q6 = *(const float4*)&Pxy_sh[24];
                const float4 q7 = *(const float4*)&Pxy_sh[28];
                Pr[0]=q0.x;  Pr[1]=q0.y;  Pr[2]=q0.z;  Pr[3]=q0.w;
                Pr[4]=q1.x;  Pr[5]=q1.y;  Pr[6]=q1.z;  Pr[7]=q1.w;
                Pr[8]=q2.x;  Pr[9]=q2.y;  Pr[10]=q2.z; Pr[11]=q2.w;
                Pr[12]=q3.x; Pr[13]=q3.y; Pr[14]=q3.z; Pr[15]=q3.w;
                Pr[16]=q4.x; Pr[17]=q4.y; Pr[18]=q4.z; Pr[19]=q4.w;
                Pr[20]=q5.x; Pr[21]=q5.y; Pr[22]=q5.z; Pr[23]=q5.w;
                Pr[24]=q6.x; Pr[25]=q6.y; Pr[26]=q6.z; Pr[27]=q6.w;
                Pr[28]=q7.x; Pr[29]=q7.y; Pr[30]=q7.z; Pr[31]=q7.w;
            }
            // P_new column k8: Pc[i] = Ppc[i] - dot(kk, Pxy row i)  (+ jitter)
            // (K*Pxy^T = K*Sy*K^T symmetric => entry (i,k8) = kk . Pxy[i])
            #pragma unroll
            for (int i = 0; i < 8; ++i) {
                const float m = kk[0] * Pr[i * 4 + 0] + kk[1] * Pr[i * 4 + 1]
                              + kk[2] * Pr[i * 4 + 2] + kk[3] * Pr[i * 4 + 3];
                Pc[i] = Ppc[i] - m + ((i == k8) ? 1e-4f : 0.0f);
            }
            // x_new: own row k8 then broadcast (lane r<8 has k8==r)
            const float4 yt = *(const float4*)&y_sh[t * 4];
            const float4 yp = *(const float4*)&ypred_sh[0];
            const float in0 = yt.x - yp.x, in1 = yt.y - yp.y;
            const float in2 = yt.z - yp.z, in3 = yt.w - yp.w;
            const float xo = xp_sh[k8]
                           + kk[0] * in0 + kk[1] * in1 + kk[2] * in2 + kk[3] * in3;
            #pragma unroll
            for (int i = 0; i < 8; ++i) xn[i] = lane_bcast(xo, i);
            // stores: coalesced 64-lane P store (lane (g8,k8) owns P[g8][k8])
            out[Pbase + (size_t)t * 64 + lane] = Pc[g8];
            if (lane == 0) {
                *(float4*)&out[Xbase + (size_t)t * 8]     = make_float4(xn[0], xn[1], xn[2], xn[3]);
                *(float4*)&out[Xbase + (size_t)t * 8 + 4] = make_float4(xn[4], xn[5], xn[6], xn[7]);
            }
        } else {
            // qe = 0.5 slogdet(P_pred): branchless column LDL, diag-only
            float aq[8];
            #pragma unroll
            for (int i = 0; i < 8; ++i) aq[i] = Pp_sh[i * 8 + k8];
            float qe = 0.0f;
            #pragma unroll
            for (int j = 0; j < 8; ++j) {
                const float dj  = lane_bcast(aq[j], j);
                qe += __logf(dj);
                const float rv2 = fast_rcp(dj);
                const float tq  = (k8 > j) ? aq[j] * rv2 : 0.0f;
                float u[8];
                #pragma unroll
                for (int i = j + 1; i < 8; ++i) u[i] = lane_bcast(aq[i], j);
                #pragma unroll
                for (int i = j + 1; i < 8; ++i) aq[i] = fmaf(-tq, u[i], aq[i]);
            }
            if (lane == 0) out[qbase + t] = 0.5f * qe;
        }
        // no trailing barrier: next-step hazards are covered by b1..b4 ordering
    }
}

extern "C" void kernel_launch(void* const* d_in, const int* in_sizes, int n_in,
                              void* d_out, int out_size, void* d_ws, size_t ws_size,
                              hipStream_t stream) {
    (void)in_sizes; (void)n_in; (void)out_size; (void)d_ws; (void)ws_size;
    const float* X0 = (const float*)d_in[0];
    const float* U  = (const float*)d_in[1];
    const float* Y  = (const float*)d_in[2];
    const float* W1 = (const float*)d_in[3];
    const float* B1 = (const float*)d_in[4];
    const float* W2 = (const float*)d_in[5];
    const float* B2 = (const float*)d_in[6];
    const float* HM = (const float*)d_in[7];
    const float* LQ = (const float*)d_in[8];
    const float* LR = (const float*)d_in[9];
    const float* LP0 = (const float*)d_in[10];
    float* out = (float*)d_out;
    ukf_kernel<<<dim3(B_LEN), dim3(128), 0, stream>>>(X0, U, Y, W1, B1, W2, B2,
                                                      HM, LQ, LR, LP0, out);
}

// Round 8
// 797.524 us; speedup vs baseline: 2.5231x; 1.0436x over previous
//
#include <hip/hip_runtime.h>
#include <math.h>

#define B_LEN 1024
#define T_LEN 256
#define HST 36   // hid_sh leading stride keeps float4 access conflict-light
#define TS 20    // dxT/ypT row stride (17 used + 3 pad): banks 20*r%32 distinct

__device__ __forceinline__ float fast_rcp(float x) { return __builtin_amdgcn_rcpf(x); }
__device__ __forceinline__ float fast_rsq(float x) { return __builtin_amdgcn_rsqf(x); }
__device__ __forceinline__ float lane_bcast(float v, int l) {
    return __int_as_float(__builtin_amdgcn_readlane(__float_as_int(v), l));
}
__device__ __forceinline__ float fast_tanh(float x) {
    float e = __expf(2.0f * x);
    return 1.0f - 2.0f * fast_rcp(e + 1.0f);
}
__device__ __forceinline__ float softplus_f(float x) {
    return (x > 20.0f) ? x : log1pf(expf(x));
}
// weighted 17-dot: 0.0625*sum(all 17) + (2-0.0625)*center  (Wc0=2, rest 1/16)
__device__ __forceinline__ float wdot17(const float* __restrict__ a,
                                        const float* __restrict__ b) {
    float full = 0.0f;
    #pragma unroll
    for (int c = 0; c < 4; ++c) {
        const float4 av = *(const float4*)&a[c * 4];
        const float4 bv = *(const float4*)&b[c * 4];
        full += av.x * bv.x + av.y * bv.y + av.z * bv.z + av.w * bv.w;
    }
    full += a[16] * b[16];
    return 0.0625f * full + 1.9375f * a[0] * b[0];
}

// R7 verified base (798us) + two local deltas:
// (G1) Phase D rebalance: Pxy moved from w0 to w1's round using the
//      R2-verified merged pattern (lanes<32 -> Pxy(ii,mm); lanes 32..47 ->
//      Sy). w0's D is now a single wdot17 round (Ppred). w1 reads dxT
//      (fenced by b3); w0 reads Pxy/Si in E (fenced by b4); cross-step
//      ordered by the b3(t+1) rendezvous.
// (G2) Pp readbacks via symmetry: Pp is EXACTLY symmetric in FP
//      (wdot17(a,b)==wdot17(b,a), identical op order), so column k8 ==
//      row k8 == contiguous -> 2x ds_read_b128 (2-way bank alias, free)
//      replaces 8 scalar LDS reads in both w0's Ppc (D) and w1's aq (E).
__global__ __launch_bounds__(128, 2)
void ukf_kernel(const float* __restrict__ X0, const float* __restrict__ U,
                const float* __restrict__ Y,  const float* __restrict__ W1,
                const float* __restrict__ B1, const float* __restrict__ W2,
                const float* __restrict__ B2, const float* __restrict__ HM,
                const float* __restrict__ LQ, const float* __restrict__ LR,
                const float* __restrict__ LP0, float* __restrict__ out)
{
    const int tid  = threadIdx.x;
    const int wid  = tid >> 6;
    const int lane = tid & 63;
    const int b    = blockIdx.x;
    const int k8   = lane & 7;        // column / j8
    const int g8   = lane >> 3;       // replica group / i8
    const int i8   = g8;
    const int j8   = k8;
    const int h32  = lane & 31;
    const int p2   = lane >> 5;       // half-wave (L1 row parity)
    const int m4   = lane & 3;
    const int sy   = lane >> 2;

    __shared__ __align__(16) float u_sh[T_LEN * 2];
    __shared__ __align__(16) float y_sh[T_LEN * 4];
    __shared__ __align__(16) float pts_sh[17 * 8];
    __shared__ __align__(16) float hid_sh[17 * HST];
    __shared__ __align__(16) float pf_sh[17 * 8];
    __shared__ __align__(16) float dxT_sh[8 * TS];   // dxT[d][s]
    __shared__ __align__(16) float ypT_sh[4 * TS];   // ypT[m][s]
    __shared__ __align__(16) float xp_sh[8];
    __shared__ __align__(16) float ypred_sh[4];
    __shared__ __align__(16) float Sy_sh[16];
    __shared__ __align__(16) float Si_sh[16];
    __shared__ __align__(16) float Pxy_sh[32];
    __shared__ __align__(16) float Pp_sh[64];

    // ---- one-time staging ----
    for (int k = tid; k < T_LEN * 2; k += 128) u_sh[k] = U[(size_t)b * (T_LEN * 2) + k];
    for (int k = tid; k < T_LEN * 4; k += 128) y_sh[k] = Y[(size_t)b * (T_LEN * 4) + k];

    float w1r[10];
    #pragma unroll
    for (int d = 0; d < 10; ++d) w1r[d] = W1[d * 32 + h32];
    const float b1r = B1[h32];
    float w2r[32];
    #pragma unroll
    for (int h = 0; h < 32; ++h) w2r[h] = W2[h * 8 + k8];
    const float b2r = B2[k8];
    float hmr[8];                              // wave1 only
    #pragma unroll
    for (int d = 0; d < 8; ++d) hmr[d] = HM[m4 * 8 + d];

    const float qdiag = softplus_f(LQ[i8]);    // w0 (i8,j8) layout
    const float rdiag = softplus_f(LR[m4]);    // w1 Sy

    const size_t Xbase = (size_t)b * T_LEN * 8;
    const size_t Pbase = (size_t)B_LEN * T_LEN * 8  + (size_t)b * T_LEN * 64;
    const size_t qbase = (size_t)B_LEN * T_LEN * 72 + (size_t)b * T_LEN;
    const size_t rbase = (size_t)B_LEN * T_LEN * 73 + (size_t)b * T_LEN;

    // ---- persistent register state (w0): x replicated, P column k8 ----
    float xn[8], Pc[8];
    {
        const float4 xa = *(const float4*)&X0[b * 8];
        const float4 xb = *(const float4*)&X0[b * 8 + 4];
        xn[0] = xa.x; xn[1] = xa.y; xn[2] = xa.z; xn[3] = xa.w;
        xn[4] = xb.x; xn[5] = xb.y; xn[6] = xb.z; xn[7] = xb.w;
        const float p0k = softplus_f(LP0[k8]);
        #pragma unroll
        for (int i = 0; i < 8; ++i) Pc[i] = (i == k8) ? p0k : 0.0f;
    }
    if (wid == 0) {
        out[Pbase + lane] = Pc[g8];                  // coalesced 64-lane P store
        if (lane == 0) {
            *(float4*)&out[Xbase]     = make_float4(xn[0], xn[1], xn[2], xn[3]);
            *(float4*)&out[Xbase + 4] = make_float4(xn[4], xn[5], xn[6], xn[7]);
            out[qbase] = 0.0f; out[rbase] = 0.0f;
        }
    }

    for (int t = 1; t < T_LEN; ++t) {
        // ===== Phase A [w0]: branchless column-chol8 of 8P+jitter -> pts =====
        if (wid == 0) {
            float a[8];
            #pragma unroll
            for (int i = 0; i < 8; ++i) a[i] = 8.0f * Pc[i] + ((i == k8) ? 1e-4f : 0.0f);
            #pragma unroll
            for (int j = 0; j < 8; ++j) {
                const float dj = lane_bcast(a[j], j);
                const float rv = fast_rsq(dj);
                const float sc = (k8 == j) ? rv : 1.0f;
                const float tc = (k8 > j) ? a[j] * (rv * rv) : 0.0f;
                float u[8];
                #pragma unroll
                for (int i = j + 1; i < 8; ++i) u[i] = lane_bcast(a[i], j);
                #pragma unroll
                for (int i = j + 1; i < 8; ++i) a[i] = sc * a[i] - tc * u[i];
                a[j] = (k8 == j) ? dj * rv : a[j];
            }
            float Lc[8];
            #pragma unroll
            for (int i = 0; i < 8; ++i) Lc[i] = (i >= k8) ? a[i] : 0.0f;
            if (g8 == 0) {
                *(float4*)&pts_sh[(1 + k8) * 8] =
                    make_float4(xn[0] + Lc[0], xn[1] + Lc[1], xn[2] + Lc[2], xn[3] + Lc[3]);
                *(float4*)&pts_sh[(1 + k8) * 8 + 4] =
                    make_float4(xn[4] + Lc[4], xn[5] + Lc[5], xn[6] + Lc[6], xn[7] + Lc[7]);
            } else if (g8 == 1) {
                *(float4*)&pts_sh[(9 + k8) * 8] =
                    make_float4(xn[0] - Lc[0], xn[1] - Lc[1], xn[2] - Lc[2], xn[3] - Lc[3]);
                *(float4*)&pts_sh[(9 + k8) * 8 + 4] =
                    make_float4(xn[4] - Lc[4], xn[5] - Lc[5], xn[6] - Lc[6], xn[7] - Lc[7]);
            } else if (g8 == 2 && k8 == 0) {
                *(float4*)&pts_sh[0] = make_float4(xn[0], xn[1], xn[2], xn[3]);
                *(float4*)&pts_sh[4] = make_float4(xn[4], xn[5], xn[6], xn[7]);
            }
        }
        __syncthreads();   // b1: pts ready

        // ===== Phase B [both]: fused L1+L2, per-wave sigma sets ===============
        {
            const float u0 = u_sh[(t - 1) * 2 + 0];
            const float u1 = u_sh[(t - 1) * 2 + 1];
            const float ub = b1r + u0 * w1r[8] + u1 * w1r[9];
            if (wid == 0) {
                #pragma unroll
                for (int p = 0; p < 4; ++p) {
                    const int s = 2 * p + p2;                 // rows 0..7
                    const float4 pa = *(const float4*)&pts_sh[s * 8];
                    const float4 pb = *(const float4*)&pts_sh[s * 8 + 4];
                    float acc = ub
                        + pa.x * w1r[0] + pa.y * w1r[1] + pa.z * w1r[2] + pa.w * w1r[3]
                        + pb.x * w1r[4] + pb.y * w1r[5] + pb.z * w1r[6] + pb.w * w1r[7];
                    hid_sh[s * HST + h32] = fast_tanh(acc);
                }
            } else {
                #pragma unroll
                for (int p = 0; p < 4; ++p) {
                    const int s = 8 + 2 * p + p2;             // rows 8..15
                    const float4 pa = *(const float4*)&pts_sh[s * 8];
                    const float4 pb = *(const float4*)&pts_sh[s * 8 + 4];
                    float acc = ub
                        + pa.x * w1r[0] + pa.y * w1r[1] + pa.z * w1r[2] + pa.w * w1r[3]
                        + pb.x * w1r[4] + pb.y * w1r[5] + pb.z * w1r[6] + pb.w * w1r[7];
                    hid_sh[s * HST + h32] = fast_tanh(acc);
                }
                if (p2 == 0) {                                // row 16
                    const float4 pa = *(const float4*)&pts_sh[16 * 8];
                    const float4 pb = *(const float4*)&pts_sh[16 * 8 + 4];
                    float acc = ub
                        + pa.x * w1r[0] + pa.y * w1r[1] + pa.z * w1r[2] + pa.w * w1r[3]
                        + pb.x * w1r[4] + pb.y * w1r[5] + pb.z * w1r[6] + pb.w * w1r[7];
                    hid_sh[16 * HST + h32] = fast_tanh(acc);
                }
            }
            // L2 on own-wave rows (same-wave DS in-order: no barrier)
            const int srow = (wid == 0) ? g8 : (8 + g8);
            float acc = b2r;
            #pragma unroll
            for (int h = 0; h < 32; h += 4) {
                const float4 hv = *(const float4*)&hid_sh[srow * HST + h];
                acc += hv.x * w2r[h] + hv.y * w2r[h + 1] + hv.z * w2r[h + 2] + hv.w * w2r[h + 3];
            }
            pf_sh[srow * 8 + k8] = pts_sh[srow * 8 + k8] + acc;
            if (wid == 1 && lane < 8) {
                float a16 = b2r;
                #pragma unroll
                for (int h = 0; h < 32; h += 4) {
                    const float4 hv = *(const float4*)&hid_sh[16 * HST + h];
                    a16 += hv.x * w2r[h] + hv.y * w2r[h + 1] + hv.z * w2r[h + 2] + hv.w * w2r[h + 3];
                }
                pf_sh[16 * 8 + lane] = pts_sh[16 * 8 + lane] + a16;
            }
        }
        __syncthreads();   // b2: pf ready

        // ===== Phase C [w0]: x_pred + dxT ; [w1]: y_pts + ypred + ypT =========
        if (wid == 0) {
            const float v0   = pf_sh[i8 * 8 + j8];
            const float v1   = pf_sh[(8 + i8) * 8 + j8];
            const float pf16 = (i8 == 0) ? pf_sh[16 * 8 + j8] : 0.0f;
            float part = ((i8 == 0) ? pf16 : v0) + v1;        // s=16 replaces s=0
            part += __shfl_xor(part, 8);
            part += __shfl_xor(part, 16);
            part += __shfl_xor(part, 32);
            const float xp = part * 0.0625f;
            if (i8 == 0) xp_sh[j8] = xp;
            dxT_sh[j8 * TS + i8]       = v0 - xp;             // dxT[d][s]
            dxT_sh[j8 * TS + 8 + i8]   = v1 - xp;
            if (i8 == 0) dxT_sh[j8 * TS + 16] = pf16 - xp;
        } else {
            float yv0, yv16 = 0.0f;
            {
                const float4 pa = *(const float4*)&pf_sh[sy * 8];
                const float4 pb = *(const float4*)&pf_sh[sy * 8 + 4];
                yv0 = pa.x * hmr[0] + pa.y * hmr[1] + pa.z * hmr[2] + pa.w * hmr[3]
                    + pb.x * hmr[4] + pb.y * hmr[5] + pb.z * hmr[6] + pb.w * hmr[7];
            }
            if (sy == 0) {
                const float4 pa = *(const float4*)&pf_sh[16 * 8];
                const float4 pb = *(const float4*)&pf_sh[16 * 8 + 4];
                yv16 = pa.x * hmr[0] + pa.y * hmr[1] + pa.z * hmr[2] + pa.w * hmr[3]
                     + pb.x * hmr[4] + pb.y * hmr[5] + pb.z * hmr[6] + pb.w * hmr[7];
            }
            float py = (sy == 0) ? yv16 : yv0;
            py += __shfl_xor(py, 4);
            py += __shfl_xor(py, 8);
            py += __shfl_xor(py, 16);
            py += __shfl_xor(py, 32);
            const float ypred = py * 0.0625f;
            if (lane < 4) ypred_sh[lane] = ypred;
            ypT_sh[m4 * TS + sy] = yv0 - ypred;               // ypT[m][s]
            if (sy == 0) ypT_sh[m4 * TS + 16] = yv16 - ypred;
        }
        __syncthreads();   // b3: dxT, ypT, xp, ypred ready

        // ===== Phase D: [w0] Ppred only ; [w1] merged Pxy+Sy -> cofactor Si ===
        float Ppc[8];
        if (wid == 0) {
            const float Ppred = wdot17(&dxT_sh[i8 * TS], &dxT_sh[j8 * TS])
                              + ((i8 == j8) ? (qdiag + 1e-4f) : 0.0f);
            Pp_sh[lane] = Ppred;
            // (G2) Pp exactly symmetric -> column k8 == row k8 (contiguous):
            // 2x ds_read_b128, 2-way bank alias (free), in-wave ordering.
            const float4 pa = *(const float4*)&Pp_sh[k8 * 8];
            const float4 pb = *(const float4*)&Pp_sh[k8 * 8 + 4];
            Ppc[0]=pa.x; Ppc[1]=pa.y; Ppc[2]=pa.z; Ppc[3]=pa.w;
            Ppc[4]=pb.x; Ppc[5]=pb.y; Ppc[6]=pb.z; Ppc[7]=pb.w;
        } else {
            // (G1) merged round (R2-verified): lanes<32 -> Pxy(ii=sy, mm=m4);
            // lanes 32..47 -> Sy(r2, m4). dxT read fenced by b3.
            const int r2 = (lane < 32) ? sy : (sy & 3);
            const float* pa2 = (lane < 32) ? &dxT_sh[r2 * TS] : &ypT_sh[r2 * TS];
            float v2 = wdot17(pa2, &ypT_sh[m4 * TS]);
            v2 += ((lane >= 32) && (r2 == m4)) ? rdiag : 0.0f;
            if (lane < 32)      Pxy_sh[lane] = v2;
            else if (lane < 48) Sy_sh[r2 * 4 + m4] = v2;
            // parallel cofactor inverse (R7-verified); Sy_sh read in-wave
            float cof;
            {
                const int i4 = sy & 3;
                const int j4 = m4;
                const int r0 = (i4 == 0) ? 1 : 0;
                const int r1 = (i4 <= 1) ? 2 : 1;
                const int rr = (i4 <= 2) ? 3 : 2;
                const int c0 = (j4 == 0) ? 1 : 0;
                const int c1 = (j4 <= 1) ? 2 : 1;
                const int cc = (j4 <= 2) ? 3 : 2;
                const float m00 = Sy_sh[r0 * 4 + c0], m01 = Sy_sh[r0 * 4 + c1], m02 = Sy_sh[r0 * 4 + cc];
                const float m10 = Sy_sh[r1 * 4 + c0], m11 = Sy_sh[r1 * 4 + c1], m12 = Sy_sh[r1 * 4 + cc];
                const float m20 = Sy_sh[rr * 4 + c0], m21 = Sy_sh[rr * 4 + c1], m22 = Sy_sh[rr * 4 + cc];
                const float d3 = m00 * (m11 * m22 - m12 * m21)
                               - m01 * (m10 * m22 - m12 * m20)
                               + m02 * (m10 * m21 - m11 * m20);
                cof = (((i4 + j4) & 1) ? -d3 : d3);
            }
            const float c0b = lane_bcast(cof, 0);
            const float c1b = lane_bcast(cof, 1);
            const float c2b = lane_bcast(cof, 2);
            const float c3b = lane_bcast(cof, 3);
            const float4 sy0 = *(const float4*)&Sy_sh[0];
            const float det = sy0.x * c0b + sy0.y * c1b + sy0.z * c2b + sy0.w * c3b;
            if (lane == 0) out[rbase + t] = 0.5f * __logf(det);
            const float rdet = fast_rcp(det);
            if (lane < 16) Si_sh[lane] = cof * rdet;
        }
        __syncthreads();   // b4: Pp / Si / Pxy ready

        // ===== Phase E: [w0] kk -> P_new(symmetric form), x_new ; [w1] qe =====
        if (wid == 0) {
            float Si[16];
            {
                const float4 a0 = *(const float4*)&Si_sh[0];
                const float4 a1 = *(const float4*)&Si_sh[4];
                const float4 a2 = *(const float4*)&Si_sh[8];
                const float4 a3 = *(const float4*)&Si_sh[12];
                Si[0]=a0.x;  Si[1]=a0.y;  Si[2]=a0.z;  Si[3]=a0.w;
                Si[4]=a1.x;  Si[5]=a1.y;  Si[6]=a1.z;  Si[7]=a1.w;
                Si[8]=a2.x;  Si[9]=a2.y;  Si[10]=a2.z; Si[11]=a2.w;
                Si[12]=a3.x; Si[13]=a3.y; Si[14]=a3.z; Si[15]=a3.w;
            }
            const float4 pr = *(const float4*)&Pxy_sh[k8 * 4];     // Pxy row k8
            float kk[4];
            #pragma unroll
            for (int aa = 0; aa < 4; ++aa)
                kk[aa] = pr.x * Si[0 * 4 + aa] + pr.y * Si[1 * 4 + aa]
                       + pr.z * Si[2 * 4 + aa] + pr.w * Si[3 * 4 + aa];
            // all 8 Pxy rows (broadcast LDS reads, compile-time indexed regs)
            float Pr[32];
            {
                const float4 q0 = *(const float4*)&Pxy_sh[0];
                const float4 q1 = *(const float4*)&Pxy_sh[4];
                const float4 q2 = *(const float4*)&Pxy_sh[8];
                const float4 q3 = *(const float4*)&Pxy_sh[12];
                const float4 q4 = *(const float4*)&Pxy_sh[16];
                const float4 q5 = *(const float4*)&Pxy_sh[20];
                const float4 q6 = *(const float4*)&Pxy_sh[24];
                const float4 q7 = *(const float4*)&Pxy_sh[28];
                Pr[0]=q0.x;  Pr[1]=q0.y;  Pr[2]=q0.z;  Pr[3]=q0.w;
                Pr[4]=q1.x;  Pr[5]=q1.y;  Pr[6]=q1.z;  Pr[7]=q1.w;
                Pr[8]=q2.x;  Pr[9]=q2.y;  Pr[10]=q2.z; Pr[11]=q2.w;
                Pr[12]=q3.x; Pr[13]=q3.y; Pr[14]=q3.z; Pr[15]=q3.w;
                Pr[16]=q4.x; Pr[17]=q4.y; Pr[18]=q4.z; Pr[19]=q4.w;
                Pr[20]=q5.x; Pr[21]=q5.y; Pr[22]=q5.z; Pr[23]=q5.w;
                Pr[24]=q6.x; Pr[25]=q6.y; Pr[26]=q6.z; Pr[27]=q6.w;
                Pr[28]=q7.x; Pr[29]=q7.y; Pr[30]=q7.z; Pr[31]=q7.w;
            }
            // P_new column k8: Pc[i] = Ppc[i] - dot(kk, Pxy row i)  (+ jitter)
            #pragma unroll
            for (int i = 0; i < 8; ++i) {
                const float m = kk[0] * Pr[i * 4 + 0] + kk[1] * Pr[i * 4 + 1]
                              + kk[2] * Pr[i * 4 + 2] + kk[3] * Pr[i * 4 + 3];
                Pc[i] = Ppc[i] - m + ((i == k8) ? 1e-4f : 0.0f);
            }
            // x_new: own row k8 then broadcast (lane r<8 has k8==r)
            const float4 yt = *(const float4*)&y_sh[t * 4];
            const float4 yp = *(const float4*)&ypred_sh[0];
            const float in0 = yt.x - yp.x, in1 = yt.y - yp.y;
            const float in2 = yt.z - yp.z, in3 = yt.w - yp.w;
            const float xo = xp_sh[k8]
                           + kk[0] * in0 + kk[1] * in1 + kk[2] * in2 + kk[3] * in3;
            #pragma unroll
            for (int i = 0; i < 8; ++i) xn[i] = lane_bcast(xo, i);
            // stores: coalesced 64-lane P store (lane (g8,k8) owns P[g8][k8])
            out[Pbase + (size_t)t * 64 + lane] = Pc[g8];
            if (lane == 0) {
                *(float4*)&out[Xbase + (size_t)t * 8]     = make_float4(xn[0], xn[1], xn[2], xn[3]);
                *(float4*)&out[Xbase + (size_t)t * 8 + 4] = make_float4(xn[4], xn[5], xn[6], xn[7]);
            }
        } else {
            // qe = 0.5 slogdet(P_pred): branchless column LDL; (G2) aq = row k8
            float aq[8];
            {
                const float4 pa = *(const float4*)&Pp_sh[k8 * 8];
                const float4 pb = *(const float4*)&Pp_sh[k8 * 8 + 4];
                aq[0]=pa.x; aq[1]=pa.y; aq[2]=pa.z; aq[3]=pa.w;
                aq[4]=pb.x; aq[5]=pb.y; aq[6]=pb.z; aq[7]=pb.w;
            }
            float qe = 0.0f;
            #pragma unroll
            for (int j = 0; j < 8; ++j) {
                const float dj  = lane_bcast(aq[j], j);
                qe += __logf(dj);
                const float rv2 = fast_rcp(dj);
                const float tq  = (k8 > j) ? aq[j] * rv2 : 0.0f;
                float u[8];
                #pragma unroll
                for (int i = j + 1; i < 8; ++i) u[i] = lane_bcast(aq[i], j);
                #pragma unroll
                for (int i = j + 1; i < 8; ++i) aq[i] = fmaf(-tq, u[i], aq[i]);
            }
            if (lane == 0) out[qbase + t] = 0.5f * qe;
        }
        // no trailing barrier: next-step hazards are covered by b1..b4 ordering
    }
}

extern "C" void kernel_launch(void* const* d_in, const int* in_sizes, int n_in,
                              void* d_out, int out_size, void* d_ws, size_t ws_size,
                              hipStream_t stream) {
    (void)in_sizes; (void)n_in; (void)out_size; (void)d_ws; (void)ws_size;
    const float* X0 = (const float*)d_in[0];
    const float* U  = (const float*)d_in[1];
    const float* Y  = (const float*)d_in[2];
    const float* W1 = (const float*)d_in[3];
    const float* B1 = (const float*)d_in[4];
    const float* W2 = (const float*)d_in[5];
    const float* B2 = (const float*)d_in[6];
    const float* HM = (const float*)d_in[7];
    const float* LQ = (const float*)d_in[8];
    const float* LR = (const float*)d_in[9];
    const float* LP0 = (const float*)d_in[10];
    float* out = (float*)d_out;
    ukf_kernel<<<dim3(B_LEN), dim3(128), 0, stream>>>(X0, U, Y, W1, B1, W2, B2,
                                                      HM, LQ, LR, LP0, out);
}